// Round 17
// baseline (403.256 us; speedup 1.0000x reference)
//
#include <hip/hip_runtime.h>

#define KC 1024
#define DD 256
#define NROWS 65536
#define BM 256
#define NT 512
#define RESCUE_EPS 0.02f
#define CHUNK 8192
#define RB 16

typedef _Float16 f16x8 __attribute__((ext_vector_type(8)));
typedef float f32x4 __attribute__((ext_vector_type(4)));

// W -> fp16 + |e_k|^2 (double-accurate)
__global__ void wprep(const float* __restrict__ W, _Float16* __restrict__ wh,
                      float* __restrict__ se) {
    int k = blockIdx.x, lane = threadIdx.x;
    float4 v = reinterpret_cast<const float4*>(W + (size_t)k * DD)[lane];
    float vv[4] = {v.x, v.y, v.z, v.w};
    _Float16 h4[4];
    double s = 0.0;
#pragma unroll
    for (int q = 0; q < 4; ++q) {
        h4[q] = (_Float16)vv[q];
        s += (double)vv[q] * vv[q];
    }
    *reinterpret_cast<uint2*>(wh + (size_t)k * DD + lane * 4) = *reinterpret_cast<uint2*>(h4);
    for (int m = 32; m >= 1; m >>= 1) s += __shfl_xor(s, m, 64);
    if (lane == 0) se[k] = (float)s;
}

// LDS-tiled transpose: WT[d][c] = W[c][d]
__global__ __launch_bounds__(256) void wtrans(const float* __restrict__ W,
                                              float* __restrict__ WT) {
    __shared__ float tile[64][65];
    const int bx = blockIdx.x;          // 0..63 = cx*4 + dx
    const int cx = bx >> 2, dx = bx & 3;
    const int t = threadIdx.x;
    for (int it = 0; it < 16; ++it) {
        int idx = it * 256 + t;
        int cl = idx >> 6, dl = idx & 63;
        tile[cl][dl] = W[(size_t)(cx * 64 + cl) * DD + dx * 64 + dl];
    }
    __syncthreads();
    for (int it = 0; it < 16; ++it) {
        int idx = it * 256 + t;
        int dl = idx >> 6, cl = idx & 63;
        WT[(size_t)(dx * 64 + dl) * KC + cx * 64 + cl] = tile[cl][dl];
    }
}

__global__ __launch_bounds__(NT, 2) void vq_mfma(
    const float* __restrict__ X, const float* __restrict__ Wf,
    const _Float16* __restrict__ wh,
    const float* __restrict__ se,
    float* __restrict__ out_q, float* __restrict__ out_idx,
    int* __restrict__ idx_int, float* __restrict__ sx_out,
    int* __restrict__ flags, int* __restrict__ count,
    float* __restrict__ counts, double* __restrict__ loss_acc)
{
    __shared__ __align__(16) _Float16 wt[2][64 * 256];  // 64 KB
    __shared__ float sxs[BM];
    __shared__ float ses[KC];
    __shared__ int argidx[BM];
    __shared__ double lred[8];

    const int tid = threadIdx.x;
    const int row0 = blockIdx.x * BM;
    const int w = tid >> 6, lane = tid & 63;
    const int m = lane & 15, g = lane >> 4;

    for (int i = tid; i < KC; i += NT) ses[i] = se[i];

    f16x8 ahr[2][8];
#pragma unroll
    for (int rt = 0; rt < 2; ++rt) {
        const float* xr = X + (size_t)(row0 + w * 32 + rt * 16 + m) * DD;
        double ss = 0.0;
#pragma unroll
        for (int ks = 0; ks < 8; ++ks) {
            float4 a = *reinterpret_cast<const float4*>(xr + ks * 32 + g * 8);
            float4 b = *reinterpret_cast<const float4*>(xr + ks * 32 + g * 8 + 4);
            float v[8] = {a.x, a.y, a.z, a.w, b.x, b.y, b.z, b.w};
            f16x8 h;
#pragma unroll
            for (int q = 0; q < 8; ++q) {
                h[q] = (_Float16)v[q];
                ss += (double)v[q] * v[q];
            }
            ahr[rt][ks] = h;
        }
        ss += __shfl_xor(ss, 16, 64);
        ss += __shfl_xor(ss, 32, 64);
        if (g == 0) sxs[w * 32 + rt * 16 + m] = (float)ss;
    }

    uint4 sreg[4];
    auto stage_load = [&](int ct) {
        int base = ct * 64;
#pragma unroll
        for (int p = 0; p < 4; ++p) {
            int idx = p * NT + tid, code = idx >> 5, c = idx & 31;
            size_t go = (size_t)(base + code) * DD + c * 8;
            sreg[p] = *reinterpret_cast<const uint4*>(wh + go);
        }
    };
    auto stage_write = [&](int buf) {
#pragma unroll
        for (int p = 0; p < 4; ++p) {
            int idx = p * NT + tid, code = idx >> 5, c = idx & 31;
            int cp = c ^ (code & 7);
            *reinterpret_cast<uint4*>(&wt[buf][code * 256 + cp * 8]) = sreg[p];
        }
    };

    stage_load(0); stage_write(0);
    __syncthreads();

    float b1[2][4], b2[2][4];
    int i1[2][4];
#pragma unroll
    for (int rt = 0; rt < 2; ++rt)
#pragma unroll
        for (int j = 0; j < 4; ++j) { b1[rt][j] = 3.4e38f; b2[rt][j] = 3.4e38f; i1[rt][j] = 0; }

    for (int ct = 0; ct < 16; ++ct) {
        const int buf = ct & 1;
        if (ct < 15) stage_load(ct + 1);
#pragma unroll
        for (int csp = 0; csp < 2; ++csp) {
            const _Float16* wth0 = &wt[buf][((csp * 2 + 0) * 16 + m) * 256];
            const _Float16* wth1 = &wt[buf][((csp * 2 + 1) * 16 + m) * 256];
            f32x4 a00 = {0.f, 0.f, 0.f, 0.f}, a01 = {0.f, 0.f, 0.f, 0.f};
            f32x4 a10 = {0.f, 0.f, 0.f, 0.f}, a11 = {0.f, 0.f, 0.f, 0.f};
#pragma unroll
            for (int ks = 0; ks < 8; ++ks) {
                int cp = ((ks * 4 + g) ^ (m & 7)) * 8;
                f16x8 bh0 = *reinterpret_cast<const f16x8*>(wth0 + cp);
                f16x8 bh1 = *reinterpret_cast<const f16x8*>(wth1 + cp);
                a00 = __builtin_amdgcn_mfma_f32_16x16x32_f16(ahr[0][ks], bh0, a00, 0, 0, 0);
                a10 = __builtin_amdgcn_mfma_f32_16x16x32_f16(ahr[1][ks], bh0, a10, 0, 0, 0);
                a01 = __builtin_amdgcn_mfma_f32_16x16x32_f16(ahr[0][ks], bh1, a01, 0, 0, 0);
                a11 = __builtin_amdgcn_mfma_f32_16x16x32_f16(ahr[1][ks], bh1, a11, 0, 0, 0);
            }
#pragma unroll
            for (int cs2 = 0; cs2 < 2; ++cs2) {
                const int code = ct * 64 + (csp * 2 + cs2) * 16 + m;
                const float sec = ses[code];
#pragma unroll
                for (int rt = 0; rt < 2; ++rt) {
                    f32x4 A = cs2 ? (rt ? a11 : a01) : (rt ? a10 : a00);
#pragma unroll
                    for (int j = 0; j < 4; ++j) {
                        float s = __fsub_rn(__fadd_rn(sxs[w * 32 + rt * 16 + g * 4 + j], sec),
                                            __fmul_rn(2.0f, A[j]));
                        if (s < b1[rt][j]) { b2[rt][j] = b1[rt][j]; b1[rt][j] = s; i1[rt][j] = code; }
                        else if (s < b2[rt][j]) { b2[rt][j] = s; }
                    }
                }
            }
        }
        if (ct < 15) stage_write(buf ^ 1);
        __syncthreads();
    }

#pragma unroll
    for (int rt = 0; rt < 2; ++rt)
#pragma unroll
        for (int j = 0; j < 4; ++j) {
            float v1 = b1[rt][j], v2 = b2[rt][j];
            int ix = i1[rt][j];
            for (int mm = 1; mm < 16; mm <<= 1) {
                float ov1 = __shfl_xor(v1, mm, 64);
                int oi = __shfl_xor(ix, mm, 64);
                float ov2 = __shfl_xor(v2, mm, 64);
                float nv2 = fminf(fminf(v2, ov2), fmaxf(v1, ov1));
                if (ov1 < v1 || (ov1 == v1 && oi < ix)) { v1 = ov1; ix = oi; }
                v2 = nv2;
            }
            if (m == 0) {
                int rl = w * 32 + rt * 16 + g * 4 + j;
                argidx[rl] = ix;
                if (v2 - v1 < RESCUE_EPS) {
                    int p = atomicAdd(count, 1);
                    flags[p] = row0 + rl;
                }
            }
        }
    __syncthreads();

    if (tid < BM) {
        int row = row0 + tid;
        int k = argidx[tid];
        idx_int[row] = k;
        out_idx[row] = (float)k;
        sx_out[row] = sxs[tid];
        atomicAdd(&counts[k], 1.0f);
    }

    // coalesced epilogue
    {
        double lacc = 0.0;
        for (int i = 0; i < 32; ++i) {
            const int rl = w * 32 + i;
            const int row = row0 + rl;
            const int k = argidx[rl];
            float4 q = reinterpret_cast<const float4*>(Wf + (size_t)k * DD)[lane];
            float4 x = reinterpret_cast<const float4*>(X + (size_t)row * DD)[lane];
            float4 df, o4;
            df.x = q.x - x.x; df.y = q.y - x.y; df.z = q.z - x.z; df.w = q.w - x.w;
            o4.x = x.x + df.x; o4.y = x.y + df.y; o4.z = x.z + df.z; o4.w = x.w + df.w;
            reinterpret_cast<float4*>(out_q + (size_t)row * DD)[lane] = o4;
            lacc += (double)df.x * df.x + (double)df.y * df.y +
                    (double)df.z * df.z + (double)df.w * df.w;
        }
        for (int mm = 32; mm >= 1; mm >>= 1) lacc += __shfl_xor(lacc, mm, 64);
        if (lane == 0) lred[w] = lacc;
    }
    __syncthreads();
    if (tid == 0) {
        double t = 0.0;
        for (int i = 0; i < 8; ++i) t += lred[i];
        atomicAdd(loss_acc, t);
    }
}

// batched rescue with COALESCED W^T reads; per-code arithmetic bit-identical to prior rounds
__global__ __launch_bounds__(256) void rescue(
    const float* __restrict__ X, const float* __restrict__ WT,
    const float* __restrict__ Wf,
    const float* __restrict__ se, const float* __restrict__ sx,
    const int* __restrict__ flags, const int* __restrict__ count,
    int* __restrict__ idx_int, float* __restrict__ out_idx,
    float* __restrict__ out_q, float* __restrict__ counts,
    double* __restrict__ loss_acc)
{
    __shared__ __align__(16) float xs[RB][DD];   // 16 KB
    __shared__ float rv[RB][256];                // 16 KB
    __shared__ int ri[RB][256];                  // 16 KB
    __shared__ float sxr_s[RB];
    __shared__ int rows_s[RB];
    __shared__ int kn_s[RB], ko_s[RB];
    __shared__ double dred[4];
    const int t = threadIdx.x;
    const int n = count[0];

    for (int base = blockIdx.x * RB; base < n; base += gridDim.x * RB) {
        const int nb = min(RB, n - base);
        for (int idx = t; idx < nb * 64; idx += 256) {
            int r = idx >> 6, c4 = idx & 63;
            float4 v = reinterpret_cast<const float4*>(X + (size_t)flags[base + r] * DD)[c4];
            *reinterpret_cast<float4*>(&xs[r][c4 * 4]) = v;
        }
        if (t < nb) { rows_s[t] = flags[base + t]; sxr_s[t] = sx[flags[base + t]]; }
        __syncthreads();

        float best[RB];
        int bidx[RB];
#pragma unroll
        for (int r = 0; r < RB; ++r) { best[r] = 3.4e38f; bidx[r] = 0; }

#pragma unroll
        for (int cc = 0; cc < 4; ++cc) {
            const int c = cc * 256 + t;
            float acc[RB];
#pragma unroll
            for (int r = 0; r < RB; ++r) acc[r] = 0.0f;
            for (int d4 = 0; d4 < 64; ++d4) {
                // coalesced: consecutive lanes read consecutive codes
                float w0 = WT[(size_t)(d4 * 4 + 0) * KC + c];
                float w1 = WT[(size_t)(d4 * 4 + 1) * KC + c];
                float w2 = WT[(size_t)(d4 * 4 + 2) * KC + c];
                float w3 = WT[(size_t)(d4 * 4 + 3) * KC + c];
#pragma unroll
                for (int r = 0; r < RB; ++r) {
                    float4 xv = *reinterpret_cast<const float4*>(&xs[r][d4 * 4]);
                    acc[r] = fmaf(xv.w, w3, fmaf(xv.z, w2,
                             fmaf(xv.y, w1, fmaf(xv.x, w0, acc[r]))));
                }
            }
            const float sec = se[c];
#pragma unroll
            for (int r = 0; r < RB; ++r) {
                float s = __fsub_rn(__fadd_rn(sxr_s[r], sec), __fmul_rn(2.0f, acc[r]));
                if (s < best[r] || (s == best[r] && c < bidx[r])) { best[r] = s; bidx[r] = c; }
            }
        }
#pragma unroll
        for (int r = 0; r < RB; ++r) { rv[r][t] = best[r]; ri[r][t] = bidx[r]; }
        __syncthreads();

        for (int sft = 128; sft >= 1; sft >>= 1) {
            if (t < sft) {
#pragma unroll
                for (int r = 0; r < RB; ++r) {
                    float ov = rv[r][t + sft];
                    int oi = ri[r][t + sft];
                    if (ov < rv[r][t] || (ov == rv[r][t] && oi < ri[r][t])) {
                        rv[r][t] = ov; ri[r][t] = oi;
                    }
                }
            }
            __syncthreads();
        }
        if (t < nb) {
            int row = rows_s[t];
            int kn = ri[t][0], ko = idx_int[row];
            kn_s[t] = kn; ko_s[t] = ko;
            if (kn != ko) {
                idx_int[row] = kn;
                out_idx[row] = (float)kn;
                atomicAdd(&counts[ko], -1.0f);
                atomicAdd(&counts[kn], 1.0f);
            }
        }
        __syncthreads();

        for (int r = 0; r < nb; ++r) {
            const int ko = ko_s[r], kn = kn_s[r];
            if (kn != ko) {
                const int row = rows_s[r];
                float x = xs[r][t];
                float qo = Wf[(size_t)ko * DD + t];
                float qn = Wf[(size_t)kn * DD + t];
                float dfn = qn - x, dfo = qo - x;
                out_q[(size_t)row * DD + t] = x + dfn;
                double dl = (double)dfn * dfn - (double)dfo * dfo;
                for (int mm = 32; mm >= 1; mm >>= 1) dl += __shfl_xor(dl, mm, 64);
                if ((t & 63) == 0) dred[t >> 6] = dl;
                __syncthreads();
                if (t == 0) atomicAdd(loss_acc, dred[0] + dred[1] + dred[2] + dred[3]);
                __syncthreads();
            }
        }
        __syncthreads();
    }
}

__global__ __launch_bounds__(256) void emb_reduce(
    const float* __restrict__ X, const int* __restrict__ idx_int,
    float* __restrict__ emb)
{
    __shared__ int list[CHUNK];
    __shared__ int cnt;
    const int k = blockIdx.x;
    const int t = threadIdx.x;
    float acc = 0.0f;
    for (int base = 0; base < NROWS; base += CHUNK) {
        if (t == 0) cnt = 0;
        __syncthreads();
        for (int i = t; i < CHUNK; i += 256) {
            if (idx_int[base + i] == k) {
                int p = atomicAdd(&cnt, 1);
                list[p] = base + i;
            }
        }
        __syncthreads();
        const int n = cnt;
        for (int i = 0; i < n; ++i)
            acc += X[(size_t)list[i] * DD + t];
        __syncthreads();
    }
    emb[(size_t)k * DD + t] = acc;
}

__global__ void fin1(const float* __restrict__ ema_cs, float* __restrict__ ncs_buf,
                     const double* __restrict__ loss_acc, float* __restrict__ out_loss,
                     float* __restrict__ n_out)
{
    __shared__ float red[1024];
    int t = threadIdx.x;
    const float OM = (float)(1.0 - 0.99);
    float ncs = __fadd_rn(__fmul_rn(0.99f, ema_cs[t]), __fmul_rn(OM, ncs_buf[t]));
    ncs_buf[t] = ncs;
    red[t] = ncs;
    __syncthreads();
    for (int s = 512; s >= 1; s >>= 1) {
        if (t < s) red[t] += red[t + s];
        __syncthreads();
    }
    if (t == 0) {
        n_out[0] = red[0];
        float el = (float)(loss_acc[0] / 16777216.0);
        out_loss[0] = __fadd_rn(el, __fmul_rn(0.25f, el));
    }
}

__global__ __launch_bounds__(256) void fin2(const float* __restrict__ ema_avg,
                                            float* __restrict__ avg_buf,
                                            const float* __restrict__ ncs,
                                            const float* __restrict__ n_ptr,
                                            float* __restrict__ out_w)
{
    int k = blockIdx.x, d = threadIdx.x;
    const float OM = (float)(1.0 - 0.99);
    const float KEPS = (float)(1024.0 * 1e-5);
    size_t i = (size_t)k * DD + d;
    float avg = __fadd_rn(__fmul_rn(0.99f, ema_avg[i]), __fmul_rn(OM, avg_buf[i]));
    float n = n_ptr[0];
    float cs = __fmul_rn(__fdiv_rn(__fadd_rn(ncs[k], 1e-5f), __fadd_rn(n, KEPS)), n);
    avg_buf[i] = avg;
    out_w[i] = __fdiv_rn(avg, cs);
}

extern "C" void kernel_launch(void* const* d_in, const int* in_sizes, int n_in,
                              void* d_out, int out_size, void* d_ws, size_t ws_size,
                              hipStream_t stream) {
    const float* X = (const float*)d_in[0];
    const float* W = (const float*)d_in[1];
    const float* ema_cs = (const float*)d_in[2];
    const float* ema_avg = (const float*)d_in[3];

    float* out = (float*)d_out;
    float* out_q    = out;
    float* out_loss = out + 16777216;
    float* out_idx  = out + 16777217;
    float* out_w    = out + 16842753;
    float* out_ncs  = out + 17104897;
    float* out_avg  = out + 17105921;

    char* ws = (char*)d_ws;
    float* se      = (float*)(ws + 0);
    float* n_ptr   = (float*)(ws + 4096);
    double* loss   = (double*)(ws + 4112);
    int*   count   = (int*)(ws + 4128);
    _Float16* wh   = (_Float16*)(ws + 8192);
    float* sx      = (float*)(ws + 1056768);
    int*   idx_int = (int*)(ws + 1318912);
    int*   flags   = (int*)(ws + 1581056);
    float* WT      = (float*)(ws + 2097152);   // 1 MB transposed codebook

    hipMemsetAsync(out_ncs, 0, 1024 * sizeof(float), stream);
    hipMemsetAsync(loss, 0, sizeof(double), stream);
    hipMemsetAsync(count, 0, sizeof(int), stream);

    wprep<<<KC, 64, 0, stream>>>(W, wh, se);
    wtrans<<<64, 256, 0, stream>>>(W, WT);
    vq_mfma<<<NROWS / BM, NT, 0, stream>>>(X, W, wh, se, out_q, out_idx,
                                           idx_int, sx, flags, count,
                                           out_ncs, loss);
    rescue<<<256, 256, 0, stream>>>(X, WT, W, se, sx, flags, count, idx_int, out_idx,
                                    out_q, out_ncs, loss);
    emb_reduce<<<KC, 256, 0, stream>>>(X, idx_int, out_avg);
    fin1<<<1, 1024, 0, stream>>>(ema_cs, out_ncs, loss, out_loss, n_ptr);
    fin2<<<KC, 256, 0, stream>>>(ema_avg, out_avg, out_ncs, n_ptr, out_w);
}

// Round 18
// 282.937 us; speedup vs baseline: 1.4252x; 1.4252x over previous
//
#include <hip/hip_runtime.h>

#define KC 1024
#define DD 256
#define NROWS 65536
#define BM 256
#define NT 512
#define RESCUE_EPS 0.02f
#define CHUNK 8192
#define RB 8

typedef _Float16 f16x8 __attribute__((ext_vector_type(8)));
typedef float f32x4 __attribute__((ext_vector_type(4)));

// W -> fp16 + |e_k|^2 (double-accurate)
__global__ void wprep(const float* __restrict__ W, _Float16* __restrict__ wh,
                      float* __restrict__ se) {
    int k = blockIdx.x, lane = threadIdx.x;
    float4 v = reinterpret_cast<const float4*>(W + (size_t)k * DD)[lane];
    float vv[4] = {v.x, v.y, v.z, v.w};
    _Float16 h4[4];
    double s = 0.0;
#pragma unroll
    for (int q = 0; q < 4; ++q) {
        h4[q] = (_Float16)vv[q];
        s += (double)vv[q] * vv[q];
    }
    *reinterpret_cast<uint2*>(wh + (size_t)k * DD + lane * 4) = *reinterpret_cast<uint2*>(h4);
    for (int m = 32; m >= 1; m >>= 1) s += __shfl_xor(s, m, 64);
    if (lane == 0) se[k] = (float)s;
}

// tiled transpose into float4 planes: WT4[d4*KC + c] = {W[c][4d4..4d4+3]}
__global__ __launch_bounds__(256) void wtrans4(const float* __restrict__ W,
                                               float4* __restrict__ WT4) {
    __shared__ __align__(16) float4 tile[64][65];
    const int c0 = blockIdx.x * 64;
    const int t = threadIdx.x;
    for (int it = 0; it < 16; ++it) {
        int idx = it * 256 + t;
        int cl = idx >> 6, d4 = idx & 63;
        tile[cl][d4] = reinterpret_cast<const float4*>(W + (size_t)(c0 + cl) * DD)[d4];
    }
    __syncthreads();
    for (int it = 0; it < 16; ++it) {
        int idx = it * 256 + t;
        int d4 = idx >> 6, cl = idx & 63;
        WT4[(size_t)d4 * KC + c0 + cl] = tile[cl][d4];
    }
}

__global__ __launch_bounds__(NT, 2) void vq_mfma(
    const float* __restrict__ X, const float* __restrict__ Wf,
    const _Float16* __restrict__ wh,
    const float* __restrict__ se,
    float* __restrict__ out_q, float* __restrict__ out_idx,
    int* __restrict__ idx_int, float* __restrict__ sx_out,
    int* __restrict__ flags, int* __restrict__ count,
    float* __restrict__ counts, double* __restrict__ loss_acc)
{
    __shared__ __align__(16) _Float16 wt[2][64 * 256];  // 64 KB
    __shared__ float sxs[BM];
    __shared__ float ses[KC];
    __shared__ int argidx[BM];
    __shared__ double lred[8];

    const int tid = threadIdx.x;
    const int row0 = blockIdx.x * BM;
    const int w = tid >> 6, lane = tid & 63;
    const int m = lane & 15, g = lane >> 4;

    for (int i = tid; i < KC; i += NT) ses[i] = se[i];

    f16x8 ahr[2][8];
#pragma unroll
    for (int rt = 0; rt < 2; ++rt) {
        const float* xr = X + (size_t)(row0 + w * 32 + rt * 16 + m) * DD;
        double ss = 0.0;
#pragma unroll
        for (int ks = 0; ks < 8; ++ks) {
            float4 a = *reinterpret_cast<const float4*>(xr + ks * 32 + g * 8);
            float4 b = *reinterpret_cast<const float4*>(xr + ks * 32 + g * 8 + 4);
            float v[8] = {a.x, a.y, a.z, a.w, b.x, b.y, b.z, b.w};
            f16x8 h;
#pragma unroll
            for (int q = 0; q < 8; ++q) {
                h[q] = (_Float16)v[q];
                ss += (double)v[q] * v[q];
            }
            ahr[rt][ks] = h;
        }
        ss += __shfl_xor(ss, 16, 64);
        ss += __shfl_xor(ss, 32, 64);
        if (g == 0) sxs[w * 32 + rt * 16 + m] = (float)ss;
    }

    uint4 sreg[4];
    auto stage_load = [&](int ct) {
        int base = ct * 64;
#pragma unroll
        for (int p = 0; p < 4; ++p) {
            int idx = p * NT + tid, code = idx >> 5, c = idx & 31;
            size_t go = (size_t)(base + code) * DD + c * 8;
            sreg[p] = *reinterpret_cast<const uint4*>(wh + go);
        }
    };
    auto stage_write = [&](int buf) {
#pragma unroll
        for (int p = 0; p < 4; ++p) {
            int idx = p * NT + tid, code = idx >> 5, c = idx & 31;
            int cp = c ^ (code & 7);
            *reinterpret_cast<uint4*>(&wt[buf][code * 256 + cp * 8]) = sreg[p];
        }
    };

    stage_load(0); stage_write(0);
    __syncthreads();

    float b1[2][4], b2[2][4];
    int i1[2][4];
#pragma unroll
    for (int rt = 0; rt < 2; ++rt)
#pragma unroll
        for (int j = 0; j < 4; ++j) { b1[rt][j] = 3.4e38f; b2[rt][j] = 3.4e38f; i1[rt][j] = 0; }

    for (int ct = 0; ct < 16; ++ct) {
        const int buf = ct & 1;
        if (ct < 15) stage_load(ct + 1);
#pragma unroll
        for (int csp = 0; csp < 2; ++csp) {
            const _Float16* wth0 = &wt[buf][((csp * 2 + 0) * 16 + m) * 256];
            const _Float16* wth1 = &wt[buf][((csp * 2 + 1) * 16 + m) * 256];
            f32x4 a00 = {0.f, 0.f, 0.f, 0.f}, a01 = {0.f, 0.f, 0.f, 0.f};
            f32x4 a10 = {0.f, 0.f, 0.f, 0.f}, a11 = {0.f, 0.f, 0.f, 0.f};
#pragma unroll
            for (int ks = 0; ks < 8; ++ks) {
                int cp = ((ks * 4 + g) ^ (m & 7)) * 8;
                f16x8 bh0 = *reinterpret_cast<const f16x8*>(wth0 + cp);
                f16x8 bh1 = *reinterpret_cast<const f16x8*>(wth1 + cp);
                a00 = __builtin_amdgcn_mfma_f32_16x16x32_f16(ahr[0][ks], bh0, a00, 0, 0, 0);
                a10 = __builtin_amdgcn_mfma_f32_16x16x32_f16(ahr[1][ks], bh0, a10, 0, 0, 0);
                a01 = __builtin_amdgcn_mfma_f32_16x16x32_f16(ahr[0][ks], bh1, a01, 0, 0, 0);
                a11 = __builtin_amdgcn_mfma_f32_16x16x32_f16(ahr[1][ks], bh1, a11, 0, 0, 0);
            }
#pragma unroll
            for (int cs2 = 0; cs2 < 2; ++cs2) {
                const int code = ct * 64 + (csp * 2 + cs2) * 16 + m;
                const float sec = ses[code];
#pragma unroll
                for (int rt = 0; rt < 2; ++rt) {
                    f32x4 A = cs2 ? (rt ? a11 : a01) : (rt ? a10 : a00);
#pragma unroll
                    for (int j = 0; j < 4; ++j) {
                        float s = __fsub_rn(__fadd_rn(sxs[w * 32 + rt * 16 + g * 4 + j], sec),
                                            __fmul_rn(2.0f, A[j]));
                        if (s < b1[rt][j]) { b2[rt][j] = b1[rt][j]; b1[rt][j] = s; i1[rt][j] = code; }
                        else if (s < b2[rt][j]) { b2[rt][j] = s; }
                    }
                }
            }
        }
        if (ct < 15) stage_write(buf ^ 1);
        __syncthreads();
    }

#pragma unroll
    for (int rt = 0; rt < 2; ++rt)
#pragma unroll
        for (int j = 0; j < 4; ++j) {
            float v1 = b1[rt][j], v2 = b2[rt][j];
            int ix = i1[rt][j];
            for (int mm = 1; mm < 16; mm <<= 1) {
                float ov1 = __shfl_xor(v1, mm, 64);
                int oi = __shfl_xor(ix, mm, 64);
                float ov2 = __shfl_xor(v2, mm, 64);
                float nv2 = fminf(fminf(v2, ov2), fmaxf(v1, ov1));
                if (ov1 < v1 || (ov1 == v1 && oi < ix)) { v1 = ov1; ix = oi; }
                v2 = nv2;
            }
            if (m == 0) {
                int rl = w * 32 + rt * 16 + g * 4 + j;
                argidx[rl] = ix;
                if (v2 - v1 < RESCUE_EPS) {
                    int p = atomicAdd(count, 1);
                    flags[p] = row0 + rl;
                }
            }
        }
    __syncthreads();

    if (tid < BM) {
        int row = row0 + tid;
        int k = argidx[tid];
        idx_int[row] = k;
        out_idx[row] = (float)k;
        sx_out[row] = sxs[tid];
        atomicAdd(&counts[k], 1.0f);
    }

    // coalesced epilogue
    {
        double lacc = 0.0;
        for (int i = 0; i < 32; ++i) {
            const int rl = w * 32 + i;
            const int row = row0 + rl;
            const int k = argidx[rl];
            float4 q = reinterpret_cast<const float4*>(Wf + (size_t)k * DD)[lane];
            float4 x = reinterpret_cast<const float4*>(X + (size_t)row * DD)[lane];
            float4 df, o4;
            df.x = q.x - x.x; df.y = q.y - x.y; df.z = q.z - x.z; df.w = q.w - x.w;
            o4.x = x.x + df.x; o4.y = x.y + df.y; o4.z = x.z + df.z; o4.w = x.w + df.w;
            reinterpret_cast<float4*>(out_q + (size_t)row * DD)[lane] = o4;
            lacc += (double)df.x * df.x + (double)df.y * df.y +
                    (double)df.z * df.z + (double)df.w * df.w;
        }
        for (int mm = 32; mm >= 1; mm >>= 1) lacc += __shfl_xor(lacc, mm, 64);
        if (lane == 0) lred[w] = lacc;
    }
    __syncthreads();
    if (tid == 0) {
        double t = 0.0;
        for (int i = 0; i < 8; ++i) t += lred[i];
        atomicAdd(loss_acc, t);
    }
}

// batched rescue: RB rows/block, coalesced WT4 float4 loads with explicit prefetch,
// per-code fp32 arithmetic identical to prior passing rounds
__global__ __launch_bounds__(256) void rescue(
    const float* __restrict__ X, const float4* __restrict__ WT4,
    const float* __restrict__ Wf,
    const float* __restrict__ se, const float* __restrict__ sx,
    const int* __restrict__ flags, const int* __restrict__ count,
    int* __restrict__ idx_int, float* __restrict__ out_idx,
    float* __restrict__ out_q, float* __restrict__ counts,
    double* __restrict__ loss_acc)
{
    __shared__ __align__(16) float xs[RB][DD];   // 8 KB
    __shared__ float rv[RB][256];                // 8 KB
    __shared__ int ri[RB][256];                  // 8 KB
    __shared__ float sxr_s[RB];
    __shared__ int rows_s[RB];
    __shared__ int kn_s[RB], ko_s[RB];
    __shared__ double dred[4];
    const int t = threadIdx.x;
    const int n = count[0];

    for (int base = blockIdx.x * RB; base < n; base += gridDim.x * RB) {
        const int nb = min(RB, n - base);
        for (int idx = t; idx < nb * 64; idx += 256) {
            int r = idx >> 6, c4 = idx & 63;
            float4 v = reinterpret_cast<const float4*>(X + (size_t)flags[base + r] * DD)[c4];
            *reinterpret_cast<float4*>(&xs[r][c4 * 4]) = v;
        }
        if (t < nb) { rows_s[t] = flags[base + t]; sxr_s[t] = sx[flags[base + t]]; }
        __syncthreads();

        float acc[4][RB];
#pragma unroll
        for (int cc = 0; cc < 4; ++cc)
#pragma unroll
            for (int r = 0; r < RB; ++r) acc[cc][r] = 0.0f;

        float4 wv[4], wn[4];
#pragma unroll
        for (int cc = 0; cc < 4; ++cc) wv[cc] = WT4[(size_t)0 * KC + cc * 256 + t];

        for (int d4 = 0; d4 < 64; ++d4) {
            const int dn = (d4 < 63) ? d4 + 1 : 63;
#pragma unroll
            for (int cc = 0; cc < 4; ++cc) wn[cc] = WT4[(size_t)dn * KC + cc * 256 + t];
#pragma unroll
            for (int r = 0; r < RB; ++r) {
                float4 xv = *reinterpret_cast<const float4*>(&xs[r][d4 * 4]);
#pragma unroll
                for (int cc = 0; cc < 4; ++cc)
                    acc[cc][r] = fmaf(xv.w, wv[cc].w, fmaf(xv.z, wv[cc].z,
                                 fmaf(xv.y, wv[cc].y, fmaf(xv.x, wv[cc].x, acc[cc][r]))));
            }
#pragma unroll
            for (int cc = 0; cc < 4; ++cc) wv[cc] = wn[cc];
        }

        float best[RB];
        int bidx[RB];
#pragma unroll
        for (int r = 0; r < RB; ++r) { best[r] = 3.4e38f; bidx[r] = 0; }
#pragma unroll
        for (int cc = 0; cc < 4; ++cc) {
            const int c = cc * 256 + t;
            const float sec = se[c];
#pragma unroll
            for (int r = 0; r < RB; ++r) {
                float s = __fsub_rn(__fadd_rn(sxr_s[r], sec), __fmul_rn(2.0f, acc[cc][r]));
                if (s < best[r] || (s == best[r] && c < bidx[r])) { best[r] = s; bidx[r] = c; }
            }
        }
#pragma unroll
        for (int r = 0; r < RB; ++r) { rv[r][t] = best[r]; ri[r][t] = bidx[r]; }
        __syncthreads();

        for (int sft = 128; sft >= 1; sft >>= 1) {
            if (t < sft) {
#pragma unroll
                for (int r = 0; r < RB; ++r) {
                    float ov = rv[r][t + sft];
                    int oi = ri[r][t + sft];
                    if (ov < rv[r][t] || (ov == rv[r][t] && oi < ri[r][t])) {
                        rv[r][t] = ov; ri[r][t] = oi;
                    }
                }
            }
            __syncthreads();
        }
        if (t < nb) {
            int row = rows_s[t];
            int kn = ri[t][0], ko = idx_int[row];
            kn_s[t] = kn; ko_s[t] = ko;
            if (kn != ko) {
                idx_int[row] = kn;
                out_idx[row] = (float)kn;
                atomicAdd(&counts[ko], -1.0f);
                atomicAdd(&counts[kn], 1.0f);
            }
        }
        __syncthreads();

        for (int r = 0; r < nb; ++r) {
            const int ko = ko_s[r], kn = kn_s[r];
            if (kn != ko) {
                const int row = rows_s[r];
                float x = xs[r][t];
                float qo = Wf[(size_t)ko * DD + t];
                float qn = Wf[(size_t)kn * DD + t];
                float dfn = qn - x, dfo = qo - x;
                out_q[(size_t)row * DD + t] = x + dfn;
                double dl = (double)dfn * dfn - (double)dfo * dfo;
                for (int mm = 32; mm >= 1; mm >>= 1) dl += __shfl_xor(dl, mm, 64);
                if ((t & 63) == 0) dred[t >> 6] = dl;
                __syncthreads();
                if (t == 0) atomicAdd(loss_acc, dred[0] + dred[1] + dred[2] + dred[3]);
                __syncthreads();
            }
        }
        __syncthreads();
    }
}

__global__ __launch_bounds__(256) void emb_reduce(
    const float* __restrict__ X, const int* __restrict__ idx_int,
    float* __restrict__ emb)
{
    __shared__ int list[CHUNK];
    __shared__ int cnt;
    const int k = blockIdx.x;
    const int t = threadIdx.x;
    float acc = 0.0f;
    for (int base = 0; base < NROWS; base += CHUNK) {
        if (t == 0) cnt = 0;
        __syncthreads();
        for (int i = t; i < CHUNK; i += 256) {
            if (idx_int[base + i] == k) {
                int p = atomicAdd(&cnt, 1);
                list[p] = base + i;
            }
        }
        __syncthreads();
        const int n = cnt;
        for (int i = 0; i < n; ++i)
            acc += X[(size_t)list[i] * DD + t];
        __syncthreads();
    }
    emb[(size_t)k * DD + t] = acc;
}

__global__ void fin1(const float* __restrict__ ema_cs, float* __restrict__ ncs_buf,
                     const double* __restrict__ loss_acc, float* __restrict__ out_loss,
                     float* __restrict__ n_out)
{
    __shared__ float red[1024];
    int t = threadIdx.x;
    const float OM = (float)(1.0 - 0.99);
    float ncs = __fadd_rn(__fmul_rn(0.99f, ema_cs[t]), __fmul_rn(OM, ncs_buf[t]));
    ncs_buf[t] = ncs;
    red[t] = ncs;
    __syncthreads();
    for (int s = 512; s >= 1; s >>= 1) {
        if (t < s) red[t] += red[t + s];
        __syncthreads();
    }
    if (t == 0) {
        n_out[0] = red[0];
        float el = (float)(loss_acc[0] / 16777216.0);
        out_loss[0] = __fadd_rn(el, __fmul_rn(0.25f, el));
    }
}

__global__ __launch_bounds__(256) void fin2(const float* __restrict__ ema_avg,
                                            float* __restrict__ avg_buf,
                                            const float* __restrict__ ncs,
                                            const float* __restrict__ n_ptr,
                                            float* __restrict__ out_w)
{
    int k = blockIdx.x, d = threadIdx.x;
    const float OM = (float)(1.0 - 0.99);
    const float KEPS = (float)(1024.0 * 1e-5);
    size_t i = (size_t)k * DD + d;
    float avg = __fadd_rn(__fmul_rn(0.99f, ema_avg[i]), __fmul_rn(OM, avg_buf[i]));
    float n = n_ptr[0];
    float cs = __fmul_rn(__fdiv_rn(__fadd_rn(ncs[k], 1e-5f), __fadd_rn(n, KEPS)), n);
    avg_buf[i] = avg;
    out_w[i] = __fdiv_rn(avg, cs);
}

extern "C" void kernel_launch(void* const* d_in, const int* in_sizes, int n_in,
                              void* d_out, int out_size, void* d_ws, size_t ws_size,
                              hipStream_t stream) {
    const float* X = (const float*)d_in[0];
    const float* W = (const float*)d_in[1];
    const float* ema_cs = (const float*)d_in[2];
    const float* ema_avg = (const float*)d_in[3];

    float* out = (float*)d_out;
    float* out_q    = out;
    float* out_loss = out + 16777216;
    float* out_idx  = out + 16777217;
    float* out_w    = out + 16842753;
    float* out_ncs  = out + 17104897;
    float* out_avg  = out + 17105921;

    char* ws = (char*)d_ws;
    float* se      = (float*)(ws + 0);
    float* n_ptr   = (float*)(ws + 4096);
    double* loss   = (double*)(ws + 4112);
    int*   count   = (int*)(ws + 4128);
    _Float16* wh   = (_Float16*)(ws + 8192);
    float* sx      = (float*)(ws + 1056768);
    int*   idx_int = (int*)(ws + 1318912);
    int*   flags   = (int*)(ws + 1581056);
    float4* WT4    = (float4*)(ws + 2097152);   // 1 MB packed transposed codebook

    hipMemsetAsync(out_ncs, 0, 1024 * sizeof(float), stream);
    hipMemsetAsync(loss, 0, sizeof(double), stream);
    hipMemsetAsync(count, 0, sizeof(int), stream);

    wprep<<<KC, 64, 0, stream>>>(W, wh, se);
    wtrans4<<<16, 256, 0, stream>>>(W, WT4);
    vq_mfma<<<NROWS / BM, NT, 0, stream>>>(X, W, wh, se, out_q, out_idx,
                                           idx_int, sx, flags, count,
                                           out_ncs, loss);
    rescue<<<1024, 256, 0, stream>>>(X, WT4, W, se, sx, flags, count, idx_int, out_idx,
                                     out_q, out_ncs, loss);
    emb_reduce<<<KC, 256, 0, stream>>>(X, idx_int, out_avg);
    fin1<<<1, 1024, 0, stream>>>(ema_cs, out_ncs, loss, out_loss, n_ptr);
    fin2<<<KC, 256, 0, stream>>>(ema_avg, out_avg, out_ncs, n_ptr, out_w);
}

// Round 19
// 256.035 us; speedup vs baseline: 1.5750x; 1.1051x over previous
//
#include <hip/hip_runtime.h>

#define KC 1024
#define DD 256
#define NROWS 65536
#define BM 256
#define NT 512
#define RESCUE_EPS 0.02f
#define CHUNK 8192
#define RB 8

typedef _Float16 f16x8 __attribute__((ext_vector_type(8)));
typedef float f32x4 __attribute__((ext_vector_type(4)));
typedef const __attribute__((address_space(1))) unsigned int* gptr_t;
typedef __attribute__((address_space(3))) unsigned int* lptr_t;

// W -> fp16 + |e_k|^2 (double-accurate)
__global__ void wprep(const float* __restrict__ W, _Float16* __restrict__ wh,
                      float* __restrict__ se) {
    int k = blockIdx.x, lane = threadIdx.x;
    float4 v = reinterpret_cast<const float4*>(W + (size_t)k * DD)[lane];
    float vv[4] = {v.x, v.y, v.z, v.w};
    _Float16 h4[4];
    double s = 0.0;
#pragma unroll
    for (int q = 0; q < 4; ++q) {
        h4[q] = (_Float16)vv[q];
        s += (double)vv[q] * vv[q];
    }
    *reinterpret_cast<uint2*>(wh + (size_t)k * DD + lane * 4) = *reinterpret_cast<uint2*>(h4);
    for (int m = 32; m >= 1; m >>= 1) s += __shfl_xor(s, m, 64);
    if (lane == 0) se[k] = (float)s;
}

// tiled transpose into float4 planes: WT4[d4*KC + c] = {W[c][4d4..4d4+3]}
__global__ __launch_bounds__(256) void wtrans4(const float* __restrict__ W,
                                               float4* __restrict__ WT4) {
    __shared__ __align__(16) float4 tile[64][65];
    const int c0 = blockIdx.x * 64;
    const int t = threadIdx.x;
    for (int it = 0; it < 16; ++it) {
        int idx = it * 256 + t;
        int cl = idx >> 6, d4 = idx & 63;
        tile[cl][d4] = reinterpret_cast<const float4*>(W + (size_t)(c0 + cl) * DD)[d4];
    }
    __syncthreads();
    for (int it = 0; it < 16; ++it) {
        int idx = it * 256 + t;
        int d4 = idx >> 6, cl = idx & 63;
        WT4[(size_t)d4 * KC + c0 + cl] = tile[cl][d4];
    }
}

__global__ __launch_bounds__(NT, 2) void vq_mfma(
    const float* __restrict__ X, const float* __restrict__ Wf,
    const _Float16* __restrict__ wh,
    const float* __restrict__ se,
    float* __restrict__ out_q, float* __restrict__ out_idx,
    int* __restrict__ idx_int, float* __restrict__ sx_out,
    int* __restrict__ flags, int* __restrict__ count,
    float* __restrict__ counts, double* __restrict__ loss_acc)
{
    // K-major swizzled tile: granule L(code,kq) = code*32 + (kq ^ (code&31)); 16B granules
    __shared__ __align__(16) _Float16 wt[2][64 * 256];  // 64 KB
    __shared__ float sxs[BM];
    __shared__ float ses[KC];
    __shared__ int argidx[BM];
    __shared__ double lred[8];

    const int tid = threadIdx.x;
    const int row0 = blockIdx.x * BM;
    const int w = tid >> 6, lane = tid & 63;
    const int m = lane & 15, g = lane >> 4;

    for (int i = tid; i < KC; i += NT) ses[i] = se[i];

    f16x8 ahr[2][8];
#pragma unroll
    for (int rt = 0; rt < 2; ++rt) {
        const float* xr = X + (size_t)(row0 + w * 32 + rt * 16 + m) * DD;
        double ss = 0.0;
#pragma unroll
        for (int ks = 0; ks < 8; ++ks) {
            float4 a = *reinterpret_cast<const float4*>(xr + ks * 32 + g * 8);
            float4 b = *reinterpret_cast<const float4*>(xr + ks * 32 + g * 8 + 4);
            float v[8] = {a.x, a.y, a.z, a.w, b.x, b.y, b.z, b.w};
            f16x8 h;
#pragma unroll
            for (int q = 0; q < 8; ++q) {
                h[q] = (_Float16)v[q];
                ss += (double)v[q] * v[q];
            }
            ahr[rt][ks] = h;
        }
        ss += __shfl_xor(ss, 16, 64);
        ss += __shfl_xor(ss, 32, 64);
        if (g == 0) sxs[w * 32 + rt * 16 + m] = (float)ss;
    }

    // direct global->LDS staging: linear dest granule gi; source kq = (gi&31)^(code&31)
    // (permutation stays inside each code's 512B block -> line-coalesced)
    auto stage = [&](int ct, int buf) {
        const int base = ct * 64;
#pragma unroll
        for (int p = 0; p < 4; ++p) {
            int gi = p * NT + tid;
            int code = gi >> 5, j = gi & 31;
            int kq = j ^ (code & 31);
            const _Float16* src = wh + (size_t)(base + code) * DD + kq * 8;
            __builtin_amdgcn_global_load_lds((gptr_t)(const void*)src,
                                             (lptr_t)(void*)&wt[buf][gi * 8], 16, 0, 0);
        }
    };

    stage(0, 0);
    __syncthreads();

    float b1[2][4], b2[2][4];
    int i1[2][4];
#pragma unroll
    for (int rt = 0; rt < 2; ++rt)
#pragma unroll
        for (int j = 0; j < 4; ++j) { b1[rt][j] = 3.4e38f; b2[rt][j] = 3.4e38f; i1[rt][j] = 0; }

    for (int ct = 0; ct < 16; ++ct) {
        const int buf = ct & 1;
        if (ct < 15) stage(ct + 1, buf ^ 1);

        const _Float16* wtb = wt[buf];
        f32x4 acc[2][4];
#pragma unroll
        for (int rt = 0; rt < 2; ++rt)
#pragma unroll
            for (int cs = 0; cs < 4; ++cs) acc[rt][cs] = (f32x4){0.f, 0.f, 0.f, 0.f};

#pragma unroll
        for (int ks = 0; ks < 8; ++ks) {
            const int kq = ks * 4 + g;
#pragma unroll
            for (int cs = 0; cs < 4; ++cs) {
                const int code = cs * 16 + m;
                const int L = code * 32 + (kq ^ (code & 31));
                f16x8 bh = *reinterpret_cast<const f16x8*>(wtb + L * 8);
                acc[0][cs] = __builtin_amdgcn_mfma_f32_16x16x32_f16(ahr[0][ks], bh, acc[0][cs], 0, 0, 0);
                acc[1][cs] = __builtin_amdgcn_mfma_f32_16x16x32_f16(ahr[1][ks], bh, acc[1][cs], 0, 0, 0);
            }
        }
#pragma unroll
        for (int cs = 0; cs < 4; ++cs) {
            const int code = ct * 64 + cs * 16 + m;
            const float sec = ses[code];
#pragma unroll
            for (int rt = 0; rt < 2; ++rt) {
#pragma unroll
                for (int j = 0; j < 4; ++j) {
                    float s = __fsub_rn(__fadd_rn(sxs[w * 32 + rt * 16 + g * 4 + j], sec),
                                        __fmul_rn(2.0f, acc[rt][cs][j]));
                    if (s < b1[rt][j]) { b2[rt][j] = b1[rt][j]; b1[rt][j] = s; i1[rt][j] = code; }
                    else if (s < b2[rt][j]) { b2[rt][j] = s; }
                }
            }
        }
        __syncthreads();
    }

#pragma unroll
    for (int rt = 0; rt < 2; ++rt)
#pragma unroll
        for (int j = 0; j < 4; ++j) {
            float v1 = b1[rt][j], v2 = b2[rt][j];
            int ix = i1[rt][j];
            for (int mm = 1; mm < 16; mm <<= 1) {
                float ov1 = __shfl_xor(v1, mm, 64);
                int oi = __shfl_xor(ix, mm, 64);
                float ov2 = __shfl_xor(v2, mm, 64);
                float nv2 = fminf(fminf(v2, ov2), fmaxf(v1, ov1));
                if (ov1 < v1 || (ov1 == v1 && oi < ix)) { v1 = ov1; ix = oi; }
                v2 = nv2;
            }
            if (m == 0) {
                int rl = w * 32 + rt * 16 + g * 4 + j;
                argidx[rl] = ix;
                if (v2 - v1 < RESCUE_EPS) {
                    int p = atomicAdd(count, 1);
                    flags[p] = row0 + rl;
                }
            }
        }
    __syncthreads();

    if (tid < BM) {
        int row = row0 + tid;
        int k = argidx[tid];
        idx_int[row] = k;
        out_idx[row] = (float)k;
        sx_out[row] = sxs[tid];
        atomicAdd(&counts[k], 1.0f);
    }

    // coalesced epilogue
    {
        double lacc = 0.0;
        for (int i = 0; i < 32; ++i) {
            const int rl = w * 32 + i;
            const int row = row0 + rl;
            const int k = argidx[rl];
            float4 q = reinterpret_cast<const float4*>(Wf + (size_t)k * DD)[lane];
            float4 x = reinterpret_cast<const float4*>(X + (size_t)row * DD)[lane];
            float4 df, o4;
            df.x = q.x - x.x; df.y = q.y - x.y; df.z = q.z - x.z; df.w = q.w - x.w;
            o4.x = x.x + df.x; o4.y = x.y + df.y; o4.z = x.z + df.z; o4.w = x.w + df.w;
            reinterpret_cast<float4*>(out_q + (size_t)row * DD)[lane] = o4;
            lacc += (double)df.x * df.x + (double)df.y * df.y +
                    (double)df.z * df.z + (double)df.w * df.w;
        }
        for (int mm = 32; mm >= 1; mm >>= 1) lacc += __shfl_xor(lacc, mm, 64);
        if (lane == 0) lred[w] = lacc;
    }
    __syncthreads();
    if (tid == 0) {
        double t = 0.0;
        for (int i = 0; i < 8; ++i) t += lred[i];
        atomicAdd(loss_acc, t);
    }
}

// batched rescue (unchanged from R18)
__global__ __launch_bounds__(256) void rescue(
    const float* __restrict__ X, const float4* __restrict__ WT4,
    const float* __restrict__ Wf,
    const float* __restrict__ se, const float* __restrict__ sx,
    const int* __restrict__ flags, const int* __restrict__ count,
    int* __restrict__ idx_int, float* __restrict__ out_idx,
    float* __restrict__ out_q, float* __restrict__ counts,
    double* __restrict__ loss_acc)
{
    __shared__ __align__(16) float xs[RB][DD];
    __shared__ float rv[RB][256];
    __shared__ int ri[RB][256];
    __shared__ float sxr_s[RB];
    __shared__ int rows_s[RB];
    __shared__ int kn_s[RB], ko_s[RB];
    __shared__ double dred[4];
    const int t = threadIdx.x;
    const int n = count[0];

    for (int base = blockIdx.x * RB; base < n; base += gridDim.x * RB) {
        const int nb = min(RB, n - base);
        for (int idx = t; idx < nb * 64; idx += 256) {
            int r = idx >> 6, c4 = idx & 63;
            float4 v = reinterpret_cast<const float4*>(X + (size_t)flags[base + r] * DD)[c4];
            *reinterpret_cast<float4*>(&xs[r][c4 * 4]) = v;
        }
        if (t < nb) { rows_s[t] = flags[base + t]; sxr_s[t] = sx[flags[base + t]]; }
        __syncthreads();

        float acc[4][RB];
#pragma unroll
        for (int cc = 0; cc < 4; ++cc)
#pragma unroll
            for (int r = 0; r < RB; ++r) acc[cc][r] = 0.0f;

        float4 wv[4], wn[4];
#pragma unroll
        for (int cc = 0; cc < 4; ++cc) wv[cc] = WT4[(size_t)0 * KC + cc * 256 + t];

        for (int d4 = 0; d4 < 64; ++d4) {
            const int dn = (d4 < 63) ? d4 + 1 : 63;
#pragma unroll
            for (int cc = 0; cc < 4; ++cc) wn[cc] = WT4[(size_t)dn * KC + cc * 256 + t];
#pragma unroll
            for (int r = 0; r < RB; ++r) {
                float4 xv = *reinterpret_cast<const float4*>(&xs[r][d4 * 4]);
#pragma unroll
                for (int cc = 0; cc < 4; ++cc)
                    acc[cc][r] = fmaf(xv.w, wv[cc].w, fmaf(xv.z, wv[cc].z,
                                 fmaf(xv.y, wv[cc].y, fmaf(xv.x, wv[cc].x, acc[cc][r]))));
            }
#pragma unroll
            for (int cc = 0; cc < 4; ++cc) wv[cc] = wn[cc];
        }

        float best[RB];
        int bidx[RB];
#pragma unroll
        for (int r = 0; r < RB; ++r) { best[r] = 3.4e38f; bidx[r] = 0; }
#pragma unroll
        for (int cc = 0; cc < 4; ++cc) {
            const int c = cc * 256 + t;
            const float sec = se[c];
#pragma unroll
            for (int r = 0; r < RB; ++r) {
                float s = __fsub_rn(__fadd_rn(sxr_s[r], sec), __fmul_rn(2.0f, acc[cc][r]));
                if (s < best[r] || (s == best[r] && c < bidx[r])) { best[r] = s; bidx[r] = c; }
            }
        }
#pragma unroll
        for (int r = 0; r < RB; ++r) { rv[r][t] = best[r]; ri[r][t] = bidx[r]; }
        __syncthreads();

        for (int sft = 128; sft >= 1; sft >>= 1) {
            if (t < sft) {
#pragma unroll
                for (int r = 0; r < RB; ++r) {
                    float ov = rv[r][t + sft];
                    int oi = ri[r][t + sft];
                    if (ov < rv[r][t] || (ov == rv[r][t] && oi < ri[r][t])) {
                        rv[r][t] = ov; ri[r][t] = oi;
                    }
                }
            }
            __syncthreads();
        }
        if (t < nb) {
            int row = rows_s[t];
            int kn = ri[t][0], ko = idx_int[row];
            kn_s[t] = kn; ko_s[t] = ko;
            if (kn != ko) {
                idx_int[row] = kn;
                out_idx[row] = (float)kn;
                atomicAdd(&counts[ko], -1.0f);
                atomicAdd(&counts[kn], 1.0f);
            }
        }
        __syncthreads();

        for (int r = 0; r < nb; ++r) {
            const int ko = ko_s[r], kn = kn_s[r];
            if (kn != ko) {
                const int row = rows_s[r];
                float x = xs[r][t];
                float qo = Wf[(size_t)ko * DD + t];
                float qn = Wf[(size_t)kn * DD + t];
                float dfn = qn - x, dfo = qo - x;
                out_q[(size_t)row * DD + t] = x + dfn;
                double dl = (double)dfn * dfn - (double)dfo * dfo;
                for (int mm = 32; mm >= 1; mm >>= 1) dl += __shfl_xor(dl, mm, 64);
                if ((t & 63) == 0) dred[t >> 6] = dl;
                __syncthreads();
                if (t == 0) atomicAdd(loss_acc, dred[0] + dred[1] + dred[2] + dred[3]);
                __syncthreads();
            }
        }
        __syncthreads();
    }
}

__global__ __launch_bounds__(256) void emb_reduce(
    const float* __restrict__ X, const int* __restrict__ idx_int,
    float* __restrict__ emb)
{
    __shared__ int list[CHUNK];
    __shared__ int cnt;
    const int k = blockIdx.x;
    const int t = threadIdx.x;
    float acc = 0.0f;
    for (int base = 0; base < NROWS; base += CHUNK) {
        if (t == 0) cnt = 0;
        __syncthreads();
        for (int i = t; i < CHUNK; i += 256) {
            if (idx_int[base + i] == k) {
                int p = atomicAdd(&cnt, 1);
                list[p] = base + i;
            }
        }
        __syncthreads();
        const int n = cnt;
        for (int i = 0; i < n; ++i)
            acc += X[(size_t)list[i] * DD + t];
        __syncthreads();
    }
    emb[(size_t)k * DD + t] = acc;
}

__global__ void fin1(const float* __restrict__ ema_cs, float* __restrict__ ncs_buf,
                     const double* __restrict__ loss_acc, float* __restrict__ out_loss,
                     float* __restrict__ n_out)
{
    __shared__ float red[1024];
    int t = threadIdx.x;
    const float OM = (float)(1.0 - 0.99);
    float ncs = __fadd_rn(__fmul_rn(0.99f, ema_cs[t]), __fmul_rn(OM, ncs_buf[t]));
    ncs_buf[t] = ncs;
    red[t] = ncs;
    __syncthreads();
    for (int s = 512; s >= 1; s >>= 1) {
        if (t < s) red[t] += red[t + s];
        __syncthreads();
    }
    if (t == 0) {
        n_out[0] = red[0];
        float el = (float)(loss_acc[0] / 16777216.0);
        out_loss[0] = __fadd_rn(el, __fmul_rn(0.25f, el));
    }
}

__global__ __launch_bounds__(256) void fin2(const float* __restrict__ ema_avg,
                                            float* __restrict__ avg_buf,
                                            const float* __restrict__ ncs,
                                            const float* __restrict__ n_ptr,
                                            float* __restrict__ out_w)
{
    int k = blockIdx.x, d = threadIdx.x;
    const float OM = (float)(1.0 - 0.99);
    const float KEPS = (float)(1024.0 * 1e-5);
    size_t i = (size_t)k * DD + d;
    float avg = __fadd_rn(__fmul_rn(0.99f, ema_avg[i]), __fmul_rn(OM, avg_buf[i]));
    float n = n_ptr[0];
    float cs = __fmul_rn(__fdiv_rn(__fadd_rn(ncs[k], 1e-5f), __fadd_rn(n, KEPS)), n);
    avg_buf[i] = avg;
    out_w[i] = __fdiv_rn(avg, cs);
}

extern "C" void kernel_launch(void* const* d_in, const int* in_sizes, int n_in,
                              void* d_out, int out_size, void* d_ws, size_t ws_size,
                              hipStream_t stream) {
    const float* X = (const float*)d_in[0];
    const float* W = (const float*)d_in[1];
    const float* ema_cs = (const float*)d_in[2];
    const float* ema_avg = (const float*)d_in[3];

    float* out = (float*)d_out;
    float* out_q    = out;
    float* out_loss = out + 16777216;
    float* out_idx  = out + 16777217;
    float* out_w    = out + 16842753;
    float* out_ncs  = out + 17104897;
    float* out_avg  = out + 17105921;

    char* ws = (char*)d_ws;
    float* se      = (float*)(ws + 0);
    float* n_ptr   = (float*)(ws + 4096);
    double* loss   = (double*)(ws + 4112);
    int*   count   = (int*)(ws + 4128);
    _Float16* wh   = (_Float16*)(ws + 8192);
    float* sx      = (float*)(ws + 1056768);
    int*   idx_int = (int*)(ws + 1318912);
    int*   flags   = (int*)(ws + 1581056);
    float4* WT4    = (float4*)(ws + 2097152);

    hipMemsetAsync(out_ncs, 0, 1024 * sizeof(float), stream);
    hipMemsetAsync(loss, 0, sizeof(double), stream);
    hipMemsetAsync(count, 0, sizeof(int), stream);

    wprep<<<KC, 64, 0, stream>>>(W, wh, se);
    wtrans4<<<16, 256, 0, stream>>>(W, WT4);
    vq_mfma<<<NROWS / BM, NT, 0, stream>>>(X, W, wh, se, out_q, out_idx,
                                           idx_int, sx, flags, count,
                                           out_ncs, loss);
    rescue<<<1024, 256, 0, stream>>>(X, WT4, W, se, sx, flags, count, idx_int, out_idx,
                                     out_q, out_ncs, loss);
    emb_reduce<<<KC, 256, 0, stream>>>(X, idx_int, out_avg);
    fin1<<<1, 1024, 0, stream>>>(ema_cs, out_ncs, loss, out_loss, n_ptr);
    fin2<<<KC, 256, 0, stream>>>(ema_avg, out_avg, out_ncs, n_ptr, out_w);
}

// Round 20
// 242.436 us; speedup vs baseline: 1.6634x; 1.0561x over previous
//
#include <hip/hip_runtime.h>

#define KC 1024
#define DD 256
#define NROWS 65536
#define BM 128
#define NT 512
#define RESCUE_EPS 0.02f
#define CHUNK 8192
#define RB 8

typedef _Float16 f16x8 __attribute__((ext_vector_type(8)));
typedef float f32x4 __attribute__((ext_vector_type(4)));
typedef const __attribute__((address_space(1))) unsigned int* gptr_t;
typedef __attribute__((address_space(3))) unsigned int* lptr_t;

// W -> fp16 + |e_k|^2 (double-accurate)
__global__ void wprep(const float* __restrict__ W, _Float16* __restrict__ wh,
                      float* __restrict__ se) {
    int k = blockIdx.x, lane = threadIdx.x;
    float4 v = reinterpret_cast<const float4*>(W + (size_t)k * DD)[lane];
    float vv[4] = {v.x, v.y, v.z, v.w};
    _Float16 h4[4];
    double s = 0.0;
#pragma unroll
    for (int q = 0; q < 4; ++q) {
        h4[q] = (_Float16)vv[q];
        s += (double)vv[q] * vv[q];
    }
    *reinterpret_cast<uint2*>(wh + (size_t)k * DD + lane * 4) = *reinterpret_cast<uint2*>(h4);
    for (int m = 32; m >= 1; m >>= 1) s += __shfl_xor(s, m, 64);
    if (lane == 0) se[k] = (float)s;
}

// tiled transpose into float4 planes: WT4[d4*KC + c] = {W[c][4d4..4d4+3]}
__global__ __launch_bounds__(256) void wtrans4(const float* __restrict__ W,
                                               float4* __restrict__ WT4) {
    __shared__ __align__(16) float4 tile[64][65];
    const int c0 = blockIdx.x * 64;
    const int t = threadIdx.x;
    for (int it = 0; it < 16; ++it) {
        int idx = it * 256 + t;
        int cl = idx >> 6, d4 = idx & 63;
        tile[cl][d4] = reinterpret_cast<const float4*>(W + (size_t)(c0 + cl) * DD)[d4];
    }
    __syncthreads();
    for (int it = 0; it < 16; ++it) {
        int idx = it * 256 + t;
        int d4 = idx >> 6, cl = idx & 63;
        WT4[(size_t)d4 * KC + c0 + cl] = tile[cl][d4];
    }
}

__global__ __launch_bounds__(NT, 2) void vq_mfma(
    const float* __restrict__ X, const float* __restrict__ Wf,
    const _Float16* __restrict__ wh,
    const float* __restrict__ se,
    float* __restrict__ out_q, float* __restrict__ out_idx,
    int* __restrict__ idx_int, float* __restrict__ sx_out,
    int* __restrict__ flags, int* __restrict__ count,
    float* __restrict__ counts, double* __restrict__ loss_acc)
{
    // K-major swizzled tile: granule L(code,kq) = code*32 + (kq ^ (code&31)); 16B granules
    __shared__ __align__(16) _Float16 wt[2][64 * 256];  // 64 KB
    __shared__ float sxs[BM];
    __shared__ float ses[KC];
    __shared__ int argidx[BM];
    __shared__ double lred[8];

    const int tid = threadIdx.x;
    const int row0 = blockIdx.x * BM;
    const int w = tid >> 6, lane = tid & 63;   // 8 waves x 16 rows
    const int m = lane & 15, g = lane >> 4;

    for (int i = tid; i < KC; i += NT) ses[i] = se[i];

    // A-fragments (fp16); |x|^2 in fp32 (argmin invariant to per-row sx offset)
    f16x8 ahr[8];
    {
        const float* xr = X + (size_t)(row0 + w * 16 + m) * DD;
        float p0 = 0.f, p1 = 0.f, p2 = 0.f, p3 = 0.f;
#pragma unroll
        for (int ks = 0; ks < 8; ++ks) {
            float4 a = *reinterpret_cast<const float4*>(xr + ks * 32 + g * 8);
            float4 b = *reinterpret_cast<const float4*>(xr + ks * 32 + g * 8 + 4);
            float v[8] = {a.x, a.y, a.z, a.w, b.x, b.y, b.z, b.w};
            f16x8 h;
#pragma unroll
            for (int q = 0; q < 8; ++q) h[q] = (_Float16)v[q];
            ahr[ks] = h;
            p0 = fmaf(v[0], v[0], fmaf(v[4], v[4], p0));
            p1 = fmaf(v[1], v[1], fmaf(v[5], v[5], p1));
            p2 = fmaf(v[2], v[2], fmaf(v[6], v[6], p2));
            p3 = fmaf(v[3], v[3], fmaf(v[7], v[7], p3));
        }
        float ss = (p0 + p1) + (p2 + p3);
        ss += __shfl_xor(ss, 16, 64);
        ss += __shfl_xor(ss, 32, 64);
        if (g == 0) sxs[w * 16 + m] = ss;
    }

    // direct global->LDS staging: linear dest granule; source kq = (gi&31)^(code&31)
    auto stage = [&](int ct, int buf) {
        const int base = ct * 64;
#pragma unroll
        for (int p = 0; p < 4; ++p) {
            int gi = p * NT + tid;
            int code = gi >> 5, j = gi & 31;
            int kq = j ^ (code & 31);
            const _Float16* src = wh + (size_t)(base + code) * DD + kq * 8;
            __builtin_amdgcn_global_load_lds((gptr_t)(const void*)src,
                                             (lptr_t)(void*)&wt[buf][gi * 8], 16, 0, 0);
        }
    };

    stage(0, 0);
    __syncthreads();

    float b1[4], b2[4];
    int i1[4];
#pragma unroll
    for (int j = 0; j < 4; ++j) { b1[j] = 3.4e38f; b2[j] = 3.4e38f; i1[j] = 0; }

    float sxr[4];
    __syncthreads();
#pragma unroll
    for (int j = 0; j < 4; ++j) sxr[j] = sxs[w * 16 + g * 4 + j];

    for (int ct = 0; ct < 16; ++ct) {
        const int buf = ct & 1;
        if (ct < 15) stage(ct + 1, buf ^ 1);

        const _Float16* wtb = wt[buf];
        f32x4 acc[4];
#pragma unroll
        for (int cs = 0; cs < 4; ++cs) acc[cs] = (f32x4){0.f, 0.f, 0.f, 0.f};

#pragma unroll
        for (int ks = 0; ks < 8; ++ks) {
            const int kq = ks * 4 + g;
#pragma unroll
            for (int cs = 0; cs < 4; ++cs) {
                const int code = cs * 16 + m;
                const int L = code * 32 + (kq ^ (code & 31));
                f16x8 bh = *reinterpret_cast<const f16x8*>(wtb + L * 8);
                acc[cs] = __builtin_amdgcn_mfma_f32_16x16x32_f16(ahr[ks], bh, acc[cs], 0, 0, 0);
            }
        }
#pragma unroll
        for (int cs = 0; cs < 4; ++cs) {
            const int code = ct * 64 + cs * 16 + m;
            const float sec = ses[code];
#pragma unroll
            for (int j = 0; j < 4; ++j) {
                float s = __fsub_rn(__fadd_rn(sxr[j], sec), __fmul_rn(2.0f, acc[cs][j]));
                if (s < b1[j]) { b2[j] = b1[j]; b1[j] = s; i1[j] = code; }
                else if (s < b2[j]) { b2[j] = s; }
            }
        }
        __syncthreads();
    }

#pragma unroll
    for (int j = 0; j < 4; ++j) {
        float v1 = b1[j], v2 = b2[j];
        int ix = i1[j];
        for (int mm = 1; mm < 16; mm <<= 1) {
            float ov1 = __shfl_xor(v1, mm, 64);
            int oi = __shfl_xor(ix, mm, 64);
            float ov2 = __shfl_xor(v2, mm, 64);
            float nv2 = fminf(fminf(v2, ov2), fmaxf(v1, ov1));
            if (ov1 < v1 || (ov1 == v1 && oi < ix)) { v1 = ov1; ix = oi; }
            v2 = nv2;
        }
        if (m == 0) {
            int rl = w * 16 + g * 4 + j;
            argidx[rl] = ix;
            if (v2 - v1 < RESCUE_EPS) {
                int p = atomicAdd(count, 1);
                flags[p] = row0 + rl;
            }
        }
    }
    __syncthreads();

    if (tid < BM) {
        int row = row0 + tid;
        int k = argidx[tid];
        idx_int[row] = k;
        out_idx[row] = (float)k;
        sx_out[row] = sxs[tid];
        atomicAdd(&counts[k], 1.0f);
    }

    // coalesced epilogue: wave w owns rows w*16..w*16+15
    {
        double lacc = 0.0;
        for (int i = 0; i < 16; ++i) {
            const int rl = w * 16 + i;
            const int row = row0 + rl;
            const int k = argidx[rl];
            float4 q = reinterpret_cast<const float4*>(Wf + (size_t)k * DD)[lane];
            float4 x = reinterpret_cast<const float4*>(X + (size_t)row * DD)[lane];
            float4 df, o4;
            df.x = q.x - x.x; df.y = q.y - x.y; df.z = q.z - x.z; df.w = q.w - x.w;
            o4.x = x.x + df.x; o4.y = x.y + df.y; o4.z = x.z + df.z; o4.w = x.w + df.w;
            reinterpret_cast<float4*>(out_q + (size_t)row * DD)[lane] = o4;
            lacc += (double)df.x * df.x + (double)df.y * df.y +
                    (double)df.z * df.z + (double)df.w * df.w;
        }
        for (int mm = 32; mm >= 1; mm >>= 1) lacc += __shfl_xor(lacc, mm, 64);
        if (lane == 0) lred[w] = lacc;
    }
    __syncthreads();
    if (tid == 0) {
        double t = 0.0;
        for (int i = 0; i < 8; ++i) t += lred[i];
        atomicAdd(loss_acc, t);
    }
}

// batched rescue (unchanged)
__global__ __launch_bounds__(256) void rescue(
    const float* __restrict__ X, const float4* __restrict__ WT4,
    const float* __restrict__ Wf,
    const float* __restrict__ se, const float* __restrict__ sx,
    const int* __restrict__ flags, const int* __restrict__ count,
    int* __restrict__ idx_int, float* __restrict__ out_idx,
    float* __restrict__ out_q, float* __restrict__ counts,
    double* __restrict__ loss_acc)
{
    __shared__ __align__(16) float xs[RB][DD];
    __shared__ float rv[RB][256];
    __shared__ int ri[RB][256];
    __shared__ float sxr_s[RB];
    __shared__ int rows_s[RB];
    __shared__ int kn_s[RB], ko_s[RB];
    __shared__ double dred[4];
    const int t = threadIdx.x;
    const int n = count[0];

    for (int base = blockIdx.x * RB; base < n; base += gridDim.x * RB) {
        const int nb = min(RB, n - base);
        for (int idx = t; idx < nb * 64; idx += 256) {
            int r = idx >> 6, c4 = idx & 63;
            float4 v = reinterpret_cast<const float4*>(X + (size_t)flags[base + r] * DD)[c4];
            *reinterpret_cast<float4*>(&xs[r][c4 * 4]) = v;
        }
        if (t < nb) { rows_s[t] = flags[base + t]; sxr_s[t] = sx[flags[base + t]]; }
        __syncthreads();

        float acc[4][RB];
#pragma unroll
        for (int cc = 0; cc < 4; ++cc)
#pragma unroll
            for (int r = 0; r < RB; ++r) acc[cc][r] = 0.0f;

        float4 wv[4], wn[4];
#pragma unroll
        for (int cc = 0; cc < 4; ++cc) wv[cc] = WT4[(size_t)0 * KC + cc * 256 + t];

        for (int d4 = 0; d4 < 64; ++d4) {
            const int dn = (d4 < 63) ? d4 + 1 : 63;
#pragma unroll
            for (int cc = 0; cc < 4; ++cc) wn[cc] = WT4[(size_t)dn * KC + cc * 256 + t];
#pragma unroll
            for (int r = 0; r < RB; ++r) {
                float4 xv = *reinterpret_cast<const float4*>(&xs[r][d4 * 4]);
#pragma unroll
                for (int cc = 0; cc < 4; ++cc)
                    acc[cc][r] = fmaf(xv.w, wv[cc].w, fmaf(xv.z, wv[cc].z,
                                 fmaf(xv.y, wv[cc].y, fmaf(xv.x, wv[cc].x, acc[cc][r]))));
            }
#pragma unroll
            for (int cc = 0; cc < 4; ++cc) wv[cc] = wn[cc];
        }

        float best[RB];
        int bidx[RB];
#pragma unroll
        for (int r = 0; r < RB; ++r) { best[r] = 3.4e38f; bidx[r] = 0; }
#pragma unroll
        for (int cc = 0; cc < 4; ++cc) {
            const int c = cc * 256 + t;
            const float sec = se[c];
#pragma unroll
            for (int r = 0; r < RB; ++r) {
                float s = __fsub_rn(__fadd_rn(sxr_s[r], sec), __fmul_rn(2.0f, acc[cc][r]));
                if (s < best[r] || (s == best[r] && c < bidx[r])) { best[r] = s; bidx[r] = c; }
            }
        }
#pragma unroll
        for (int r = 0; r < RB; ++r) { rv[r][t] = best[r]; ri[r][t] = bidx[r]; }
        __syncthreads();

        for (int sft = 128; sft >= 1; sft >>= 1) {
            if (t < sft) {
#pragma unroll
                for (int r = 0; r < RB; ++r) {
                    float ov = rv[r][t + sft];
                    int oi = ri[r][t + sft];
                    if (ov < rv[r][t] || (ov == rv[r][t] && oi < ri[r][t])) {
                        rv[r][t] = ov; ri[r][t] = oi;
                    }
                }
            }
            __syncthreads();
        }
        if (t < nb) {
            int row = rows_s[t];
            int kn = ri[t][0], ko = idx_int[row];
            kn_s[t] = kn; ko_s[t] = ko;
            if (kn != ko) {
                idx_int[row] = kn;
                out_idx[row] = (float)kn;
                atomicAdd(&counts[ko], -1.0f);
                atomicAdd(&counts[kn], 1.0f);
            }
        }
        __syncthreads();

        for (int r = 0; r < nb; ++r) {
            const int ko = ko_s[r], kn = kn_s[r];
            if (kn != ko) {
                const int row = rows_s[r];
                float x = xs[r][t];
                float qo = Wf[(size_t)ko * DD + t];
                float qn = Wf[(size_t)kn * DD + t];
                float dfn = qn - x, dfo = qo - x;
                out_q[(size_t)row * DD + t] = x + dfn;
                double dl = (double)dfn * dfn - (double)dfo * dfo;
                for (int mm = 32; mm >= 1; mm >>= 1) dl += __shfl_xor(dl, mm, 64);
                if ((t & 63) == 0) dred[t >> 6] = dl;
                __syncthreads();
                if (t == 0) atomicAdd(loss_acc, dred[0] + dred[1] + dred[2] + dred[3]);
                __syncthreads();
            }
        }
        __syncthreads();
    }
}

__global__ __launch_bounds__(256) void emb_reduce(
    const float* __restrict__ X, const int* __restrict__ idx_int,
    float* __restrict__ emb)
{
    __shared__ int list[CHUNK];
    __shared__ int cnt;
    const int k = blockIdx.x;
    const int t = threadIdx.x;
    float acc = 0.0f;
    for (int base = 0; base < NROWS; base += CHUNK) {
        if (t == 0) cnt = 0;
        __syncthreads();
        for (int i = t; i < CHUNK; i += 256) {
            if (idx_int[base + i] == k) {
                int p = atomicAdd(&cnt, 1);
                list[p] = base + i;
            }
        }
        __syncthreads();
        const int n = cnt;
        for (int i = 0; i < n; ++i)
            acc += X[(size_t)list[i] * DD + t];
        __syncthreads();
    }
    emb[(size_t)k * DD + t] = acc;
}

__global__ void fin1(const float* __restrict__ ema_cs, float* __restrict__ ncs_buf,
                     const double* __restrict__ loss_acc, float* __restrict__ out_loss,
                     float* __restrict__ n_out)
{
    __shared__ float red[1024];
    int t = threadIdx.x;
    const float OM = (float)(1.0 - 0.99);
    float ncs = __fadd_rn(__fmul_rn(0.99f, ema_cs[t]), __fmul_rn(OM, ncs_buf[t]));
    ncs_buf[t] = ncs;
    red[t] = ncs;
    __syncthreads();
    for (int s = 512; s >= 1; s >>= 1) {
        if (t < s) red[t] += red[t + s];
        __syncthreads();
    }
    if (t == 0) {
        n_out[0] = red[0];
        float el = (float)(loss_acc[0] / 16777216.0);
        out_loss[0] = __fadd_rn(el, __fmul_rn(0.25f, el));
    }
}

__global__ __launch_bounds__(256) void fin2(const float* __restrict__ ema_avg,
                                            float* __restrict__ avg_buf,
                                            const float* __restrict__ ncs,
                                            const float* __restrict__ n_ptr,
                                            float* __restrict__ out_w)
{
    int k = blockIdx.x, d = threadIdx.x;
    const float OM = (float)(1.0 - 0.99);
    const float KEPS = (float)(1024.0 * 1e-5);
    size_t i = (size_t)k * DD + d;
    float avg = __fadd_rn(__fmul_rn(0.99f, ema_avg[i]), __fmul_rn(OM, avg_buf[i]));
    float n = n_ptr[0];
    float cs = __fmul_rn(__fdiv_rn(__fadd_rn(ncs[k], 1e-5f), __fadd_rn(n, KEPS)), n);
    avg_buf[i] = avg;
    out_w[i] = __fdiv_rn(avg, cs);
}

extern "C" void kernel_launch(void* const* d_in, const int* in_sizes, int n_in,
                              void* d_out, int out_size, void* d_ws, size_t ws_size,
                              hipStream_t stream) {
    const float* X = (const float*)d_in[0];
    const float* W = (const float*)d_in[1];
    const float* ema_cs = (const float*)d_in[2];
    const float* ema_avg = (const float*)d_in[3];

    float* out = (float*)d_out;
    float* out_q    = out;
    float* out_loss = out + 16777216;
    float* out_idx  = out + 16777217;
    float* out_w    = out + 16842753;
    float* out_ncs  = out + 17104897;
    float* out_avg  = out + 17105921;

    char* ws = (char*)d_ws;
    float* se      = (float*)(ws + 0);
    float* n_ptr   = (float*)(ws + 4096);
    double* loss   = (double*)(ws + 4112);
    int*   count   = (int*)(ws + 4128);
    _Float16* wh   = (_Float16*)(ws + 8192);
    float* sx      = (float*)(ws + 1056768);
    int*   idx_int = (int*)(ws + 1318912);
    int*   flags   = (int*)(ws + 1581056);
    float4* WT4    = (float4*)(ws + 2097152);

    hipMemsetAsync(out_ncs, 0, 1024 * sizeof(float), stream);
    hipMemsetAsync(loss, 0, sizeof(double), stream);
    hipMemsetAsync(count, 0, sizeof(int), stream);

    wprep<<<KC, 64, 0, stream>>>(W, wh, se);
    wtrans4<<<16, 256, 0, stream>>>(W, WT4);
    vq_mfma<<<NROWS / BM, NT, 0, stream>>>(X, W, wh, se, out_q, out_idx,
                                           idx_int, sx, flags, count,
                                           out_ncs, loss);
    rescue<<<1024, 256, 0, stream>>>(X, WT4, W, se, sx, flags, count, idx_int, out_idx,
                                     out_q, out_ncs, loss);
    emb_reduce<<<KC, 256, 0, stream>>>(X, idx_int, out_avg);
    fin1<<<1, 1024, 0, stream>>>(ema_cs, out_ncs, loss, out_loss, n_ptr);
    fin2<<<KC, 256, 0, stream>>>(ema_avg, out_avg, out_ncs, n_ptr, out_w);
}

// Round 21
// 226.992 us; speedup vs baseline: 1.7765x; 1.0680x over previous
//
#include <hip/hip_runtime.h>

#define KC 1024
#define DD 256
#define NROWS 65536
#define BM 128
#define NT 512
#define RESCUE_EPS 0.02f
#define CHUNK 8192
#define RB 2

typedef _Float16 f16x8 __attribute__((ext_vector_type(8)));
typedef float f32x4 __attribute__((ext_vector_type(4)));
typedef const __attribute__((address_space(1))) unsigned int* gptr_t;
typedef __attribute__((address_space(3))) unsigned int* lptr_t;

// W -> fp16 + |e_k|^2 (double-accurate)
__global__ void wprep(const float* __restrict__ W, _Float16* __restrict__ wh,
                      float* __restrict__ se) {
    int k = blockIdx.x, lane = threadIdx.x;
    float4 v = reinterpret_cast<const float4*>(W + (size_t)k * DD)[lane];
    float vv[4] = {v.x, v.y, v.z, v.w};
    _Float16 h4[4];
    double s = 0.0;
#pragma unroll
    for (int q = 0; q < 4; ++q) {
        h4[q] = (_Float16)vv[q];
        s += (double)vv[q] * vv[q];
    }
    *reinterpret_cast<uint2*>(wh + (size_t)k * DD + lane * 4) = *reinterpret_cast<uint2*>(h4);
    for (int m = 32; m >= 1; m >>= 1) s += __shfl_xor(s, m, 64);
    if (lane == 0) se[k] = (float)s;
}

// tiled transpose into float4 planes: WT4[d4*KC + c] = {W[c][4d4..4d4+3]}
__global__ __launch_bounds__(256) void wtrans4(const float* __restrict__ W,
                                               float4* __restrict__ WT4) {
    __shared__ __align__(16) float4 tile[64][65];
    const int c0 = blockIdx.x * 64;
    const int t = threadIdx.x;
    for (int it = 0; it < 16; ++it) {
        int idx = it * 256 + t;
        int cl = idx >> 6, d4 = idx & 63;
        tile[cl][d4] = reinterpret_cast<const float4*>(W + (size_t)(c0 + cl) * DD)[d4];
    }
    __syncthreads();
    for (int it = 0; it < 16; ++it) {
        int idx = it * 256 + t;
        int d4 = idx >> 6, cl = idx & 63;
        WT4[(size_t)d4 * KC + c0 + cl] = tile[cl][d4];
    }
}

__global__ __launch_bounds__(NT, 2) void vq_mfma(
    const float* __restrict__ X,
    const _Float16* __restrict__ wh,
    const float* __restrict__ se,
    float* __restrict__ out_q, float* __restrict__ out_idx,
    int* __restrict__ idx_int, float* __restrict__ sx_out,
    int* __restrict__ flags, int* __restrict__ count,
    float* __restrict__ counts, double* __restrict__ loss_acc)
{
    __shared__ __align__(16) _Float16 wt[2][64 * 256];  // 64 KB
    __shared__ float sxs[BM];
    __shared__ float ses[KC];
    __shared__ int argidx[BM];
    __shared__ double lred[8];

    const int tid = threadIdx.x;
    const int row0 = blockIdx.x * BM;
    const int w = tid >> 6, lane = tid & 63;   // 8 waves x 16 rows
    const int m = lane & 15, g = lane >> 4;

    for (int i = tid; i < KC; i += NT) ses[i] = se[i];

    f16x8 ahr[8];
    {
        const float* xr = X + (size_t)(row0 + w * 16 + m) * DD;
        float p0 = 0.f, p1 = 0.f, p2 = 0.f, p3 = 0.f;
#pragma unroll
        for (int ks = 0; ks < 8; ++ks) {
            float4 a = *reinterpret_cast<const float4*>(xr + ks * 32 + g * 8);
            float4 b = *reinterpret_cast<const float4*>(xr + ks * 32 + g * 8 + 4);
            float v[8] = {a.x, a.y, a.z, a.w, b.x, b.y, b.z, b.w};
            f16x8 h;
#pragma unroll
            for (int q = 0; q < 8; ++q) h[q] = (_Float16)v[q];
            ahr[ks] = h;
            p0 = fmaf(v[0], v[0], fmaf(v[4], v[4], p0));
            p1 = fmaf(v[1], v[1], fmaf(v[5], v[5], p1));
            p2 = fmaf(v[2], v[2], fmaf(v[6], v[6], p2));
            p3 = fmaf(v[3], v[3], fmaf(v[7], v[7], p3));
        }
        float ss = (p0 + p1) + (p2 + p3);
        ss += __shfl_xor(ss, 16, 64);
        ss += __shfl_xor(ss, 32, 64);
        if (g == 0) sxs[w * 16 + m] = ss;
    }

    auto stage = [&](int ct, int buf) {
        const int base = ct * 64;
#pragma unroll
        for (int p = 0; p < 4; ++p) {
            int gi = p * NT + tid;
            int code = gi >> 5, j = gi & 31;
            int kq = j ^ (code & 31);
            const _Float16* src = wh + (size_t)(base + code) * DD + kq * 8;
            __builtin_amdgcn_global_load_lds((gptr_t)(const void*)src,
                                             (lptr_t)(void*)&wt[buf][gi * 8], 16, 0, 0);
        }
    };

    stage(0, 0);
    __syncthreads();

    float b1[4], b2[4];
    int i1[4];
#pragma unroll
    for (int j = 0; j < 4; ++j) { b1[j] = 3.4e38f; b2[j] = 3.4e38f; i1[j] = 0; }

    float sxr[4];
#pragma unroll
    for (int j = 0; j < 4; ++j) sxr[j] = sxs[w * 16 + g * 4 + j];

    for (int ct = 0; ct < 16; ++ct) {
        const int buf = ct & 1;
        if (ct < 15) stage(ct + 1, buf ^ 1);

        const _Float16* wtb = wt[buf];
        f32x4 acc[4];
#pragma unroll
        for (int cs = 0; cs < 4; ++cs) acc[cs] = (f32x4){0.f, 0.f, 0.f, 0.f};

#pragma unroll
        for (int ks = 0; ks < 8; ++ks) {
            const int kq = ks * 4 + g;
#pragma unroll
            for (int cs = 0; cs < 4; ++cs) {
                const int code = cs * 16 + m;
                const int L = code * 32 + (kq ^ (code & 31));
                f16x8 bh = *reinterpret_cast<const f16x8*>(wtb + L * 8);
                acc[cs] = __builtin_amdgcn_mfma_f32_16x16x32_f16(ahr[ks], bh, acc[cs], 0, 0, 0);
            }
        }
#pragma unroll
        for (int cs = 0; cs < 4; ++cs) {
            const int code = ct * 64 + cs * 16 + m;
            const float sec = ses[code];
#pragma unroll
            for (int j = 0; j < 4; ++j) {
                float s = __fsub_rn(__fadd_rn(sxr[j], sec), __fmul_rn(2.0f, acc[cs][j]));
                if (s < b1[j]) { b2[j] = b1[j]; b1[j] = s; i1[j] = code; }
                else if (s < b2[j]) { b2[j] = s; }
            }
        }
        __syncthreads();
    }

#pragma unroll
    for (int j = 0; j < 4; ++j) {
        float v1 = b1[j], v2 = b2[j];
        int ix = i1[j];
        for (int mm = 1; mm < 16; mm <<= 1) {
            float ov1 = __shfl_xor(v1, mm, 64);
            int oi = __shfl_xor(ix, mm, 64);
            float ov2 = __shfl_xor(v2, mm, 64);
            float nv2 = fminf(fminf(v2, ov2), fmaxf(v1, ov1));
            if (ov1 < v1 || (ov1 == v1 && oi < ix)) { v1 = ov1; ix = oi; }
            v2 = nv2;
        }
        if (m == 0) {
            int rl = w * 16 + g * 4 + j;
            argidx[rl] = ix;
            if (v2 - v1 < RESCUE_EPS) {
                int p = atomicAdd(count, 1);
                flags[p] = row0 + rl;
            }
        }
    }
    __syncthreads();

    if (tid < BM) {
        int row = row0 + tid;
        int k = argidx[tid];
        idx_int[row] = k;
        out_idx[row] = (float)k;
        sx_out[row] = sxs[tid];
        atomicAdd(&counts[k], 1.0f);
    }

    // register epilogue: x from ahr (fp16), q from wh[k] (fp16); no X re-read.
    // out_q/loss tolerance is 20.48 -> fp16 reconstruction error (~1e-2) is safe.
    {
        double lacc = 0.0;
        const int rl = w * 16 + m;
        const int row = row0 + rl;
        const int k = argidx[rl];
        const _Float16* qh = wh + (size_t)k * DD;
        float* orow = out_q + (size_t)row * DD;
#pragma unroll
        for (int ks = 0; ks < 8; ++ks) {
            const int col = ks * 32 + g * 8;
            union { uint4 u; _Float16 h[8]; } qv, xv;
            qv.u = *reinterpret_cast<const uint4*>(qh + col);
            xv.u = *reinterpret_cast<uint4*>(&ahr[ks]);
            float o8[8];
#pragma unroll
            for (int q = 0; q < 8; ++q) {
                float xf = (float)xv.h[q];
                float qf = (float)qv.h[q];
                float df = qf - xf;
                o8[q] = xf + df;
                lacc += (double)df * df;
            }
            *reinterpret_cast<float4*>(orow + col)     = *reinterpret_cast<float4*>(&o8[0]);
            *reinterpret_cast<float4*>(orow + col + 4) = *reinterpret_cast<float4*>(&o8[4]);
        }
        for (int mm = 32; mm >= 1; mm >>= 1) lacc += __shfl_xor(lacc, mm, 64);
        if (lane == 0) lred[w] = lacc;
    }
    __syncthreads();
    if (tid == 0) {
        double t = 0.0;
        for (int i = 0; i < 8; ++i) t += lred[i];
        atomicAdd(loss_acc, t);
    }
}

// batched rescue: RB=2 rows/block for max parallelism, no spill; exact-fp32 scan
__global__ __launch_bounds__(256) void rescue(
    const float* __restrict__ X, const float4* __restrict__ WT4,
    const float* __restrict__ Wf,
    const float* __restrict__ se, const float* __restrict__ sx,
    const int* __restrict__ flags, const int* __restrict__ count,
    int* __restrict__ idx_int, float* __restrict__ out_idx,
    float* __restrict__ out_q, float* __restrict__ counts,
    double* __restrict__ loss_acc)
{
    __shared__ __align__(16) float xs[RB][DD];
    __shared__ float rv[RB][256];
    __shared__ int ri[RB][256];
    __shared__ float sxr_s[RB];
    __shared__ int rows_s[RB];
    __shared__ int kn_s[RB], ko_s[RB];
    __shared__ double dred[4];
    const int t = threadIdx.x;
    const int n = count[0];

    for (int base = blockIdx.x * RB; base < n; base += gridDim.x * RB) {
        const int nb = min(RB, n - base);
        for (int idx = t; idx < nb * 64; idx += 256) {
            int r = idx >> 6, c4 = idx & 63;
            float4 v = reinterpret_cast<const float4*>(X + (size_t)flags[base + r] * DD)[c4];
            *reinterpret_cast<float4*>(&xs[r][c4 * 4]) = v;
        }
        if (t < nb) { rows_s[t] = flags[base + t]; sxr_s[t] = sx[flags[base + t]]; }
        __syncthreads();

        float acc[4][RB];
#pragma unroll
        for (int cc = 0; cc < 4; ++cc)
#pragma unroll
            for (int r = 0; r < RB; ++r) acc[cc][r] = 0.0f;

        float4 wv[4], wn[4];
#pragma unroll
        for (int cc = 0; cc < 4; ++cc) wv[cc] = WT4[(size_t)0 * KC + cc * 256 + t];

        for (int d4 = 0; d4 < 64; ++d4) {
            const int dn = (d4 < 63) ? d4 + 1 : 63;
#pragma unroll
            for (int cc = 0; cc < 4; ++cc) wn[cc] = WT4[(size_t)dn * KC + cc * 256 + t];
#pragma unroll
            for (int r = 0; r < RB; ++r) {
                float4 xv = *reinterpret_cast<const float4*>(&xs[r][d4 * 4]);
#pragma unroll
                for (int cc = 0; cc < 4; ++cc)
                    acc[cc][r] = fmaf(xv.w, wv[cc].w, fmaf(xv.z, wv[cc].z,
                                 fmaf(xv.y, wv[cc].y, fmaf(xv.x, wv[cc].x, acc[cc][r]))));
            }
#pragma unroll
            for (int cc = 0; cc < 4; ++cc) wv[cc] = wn[cc];
        }

        float best[RB];
        int bidx[RB];
#pragma unroll
        for (int r = 0; r < RB; ++r) { best[r] = 3.4e38f; bidx[r] = 0; }
#pragma unroll
        for (int cc = 0; cc < 4; ++cc) {
            const int c = cc * 256 + t;
            const float sec = se[c];
#pragma unroll
            for (int r = 0; r < RB; ++r) {
                float s = __fsub_rn(__fadd_rn(sxr_s[r], sec), __fmul_rn(2.0f, acc[cc][r]));
                if (s < best[r] || (s == best[r] && c < bidx[r])) { best[r] = s; bidx[r] = c; }
            }
        }
#pragma unroll
        for (int r = 0; r < RB; ++r) { rv[r][t] = best[r]; ri[r][t] = bidx[r]; }
        __syncthreads();

        for (int sft = 128; sft >= 1; sft >>= 1) {
            if (t < sft) {
#pragma unroll
                for (int r = 0; r < RB; ++r) {
                    float ov = rv[r][t + sft];
                    int oi = ri[r][t + sft];
                    if (ov < rv[r][t] || (ov == rv[r][t] && oi < ri[r][t])) {
                        rv[r][t] = ov; ri[r][t] = oi;
                    }
                }
            }
            __syncthreads();
        }
        if (t < nb) {
            int row = rows_s[t];
            int kn = ri[t][0], ko = idx_int[row];
            kn_s[t] = kn; ko_s[t] = ko;
            if (kn != ko) {
                idx_int[row] = kn;
                out_idx[row] = (float)kn;
                atomicAdd(&counts[ko], -1.0f);
                atomicAdd(&counts[kn], 1.0f);
            }
        }
        __syncthreads();

        for (int r = 0; r < nb; ++r) {
            const int ko = ko_s[r], kn = kn_s[r];
            if (kn != ko) {
                const int row = rows_s[r];
                float x = xs[r][t];
                float qo = Wf[(size_t)ko * DD + t];
                float qn = Wf[(size_t)kn * DD + t];
                float dfn = qn - x, dfo = qo - x;
                out_q[(size_t)row * DD + t] = x + dfn;
                double dl = (double)dfn * dfn - (double)dfo * dfo;
                for (int mm = 32; mm >= 1; mm >>= 1) dl += __shfl_xor(dl, mm, 64);
                if ((t & 63) == 0) dred[t >> 6] = dl;
                __syncthreads();
                if (t == 0) atomicAdd(loss_acc, dred[0] + dred[1] + dred[2] + dred[3]);
                __syncthreads();
            }
        }
        __syncthreads();
    }
}

__global__ __launch_bounds__(256) void emb_reduce(
    const float* __restrict__ X, const int* __restrict__ idx_int,
    float* __restrict__ emb)
{
    __shared__ int list[CHUNK];
    __shared__ int cnt;
    const int k = blockIdx.x;
    const int t = threadIdx.x;
    float acc = 0.0f;
    for (int base = 0; base < NROWS; base += CHUNK) {
        if (t == 0) cnt = 0;
        __syncthreads();
        for (int i = t; i < CHUNK; i += 256) {
            if (idx_int[base + i] == k) {
                int p = atomicAdd(&cnt, 1);
                list[p] = base + i;
            }
        }
        __syncthreads();
        const int n = cnt;
        for (int i = 0; i < n; ++i)
            acc += X[(size_t)list[i] * DD + t];
        __syncthreads();
    }
    emb[(size_t)k * DD + t] = acc;
}

__global__ void fin1(const float* __restrict__ ema_cs, float* __restrict__ ncs_buf,
                     const double* __restrict__ loss_acc, float* __restrict__ out_loss,
                     float* __restrict__ n_out)
{
    __shared__ float red[1024];
    int t = threadIdx.x;
    const float OM = (float)(1.0 - 0.99);
    float ncs = __fadd_rn(__fmul_rn(0.99f, ema_cs[t]), __fmul_rn(OM, ncs_buf[t]));
    ncs_buf[t] = ncs;
    red[t] = ncs;
    __syncthreads();
    for (int s = 512; s >= 1; s >>= 1) {
        if (t < s) red[t] += red[t + s];
        __syncthreads();
    }
    if (t == 0) {
        n_out[0] = red[0];
        float el = (float)(loss_acc[0] / 16777216.0);
        out_loss[0] = __fadd_rn(el, __fmul_rn(0.25f, el));
    }
}

__global__ __launch_bounds__(256) void fin2(const float* __restrict__ ema_avg,
                                            float* __restrict__ avg_buf,
                                            const float* __restrict__ ncs,
                                            const float* __restrict__ n_ptr,
                                            float* __restrict__ out_w)
{
    int k = blockIdx.x, d = threadIdx.x;
    const float OM = (float)(1.0 - 0.99);
    const float KEPS = (float)(1024.0 * 1e-5);
    size_t i = (size_t)k * DD + d;
    float avg = __fadd_rn(__fmul_rn(0.99f, ema_avg[i]), __fmul_rn(OM, avg_buf[i]));
    float n = n_ptr[0];
    float cs = __fmul_rn(__fdiv_rn(__fadd_rn(ncs[k], 1e-5f), __fadd_rn(n, KEPS)), n);
    avg_buf[i] = avg;
    out_w[i] = __fdiv_rn(avg, cs);
}

extern "C" void kernel_launch(void* const* d_in, const int* in_sizes, int n_in,
                              void* d_out, int out_size, void* d_ws, size_t ws_size,
                              hipStream_t stream) {
    const float* X = (const float*)d_in[0];
    const float* W = (const float*)d_in[1];
    const float* ema_cs = (const float*)d_in[2];
    const float* ema_avg = (const float*)d_in[3];

    float* out = (float*)d_out;
    float* out_q    = out;
    float* out_loss = out + 16777216;
    float* out_idx  = out + 16777217;
    float* out_w    = out + 16842753;
    float* out_ncs  = out + 17104897;
    float* out_avg  = out + 17105921;

    char* ws = (char*)d_ws;
    float* se      = (float*)(ws + 0);
    float* n_ptr   = (float*)(ws + 4096);
    double* loss   = (double*)(ws + 4112);
    int*   count   = (int*)(ws + 4128);
    _Float16* wh   = (_Float16*)(ws + 8192);
    float* sx      = (float*)(ws + 1056768);
    int*   idx_int = (int*)(ws + 1318912);
    int*   flags   = (int*)(ws + 1581056);
    float4* WT4    = (float4*)(ws + 2097152);

    hipMemsetAsync(out_ncs, 0, 1024 * sizeof(float), stream);
    hipMemsetAsync(loss, 0, sizeof(double), stream);
    hipMemsetAsync(count, 0, sizeof(int), stream);

    wprep<<<KC, 64, 0, stream>>>(W, wh, se);
    wtrans4<<<16, 256, 0, stream>>>(W, WT4);
    vq_mfma<<<NROWS / BM, NT, 0, stream>>>(X, wh, se, out_q, out_idx,
                                           idx_int, sx, flags, count,
                                           out_ncs, loss);
    rescue<<<2048, 256, 0, stream>>>(X, WT4, W, se, sx, flags, count, idx_int, out_idx,
                                     out_q, out_ncs, loss);
    emb_reduce<<<KC, 256, 0, stream>>>(X, idx_int, out_avg);
    fin1<<<1, 1024, 0, stream>>>(ema_cs, out_ncs, loss, out_loss, n_ptr);
    fin2<<<KC, 256, 0, stream>>>(ema_avg, out_avg, out_ncs, n_ptr, out_w);
}

// Round 22
// 188.896 us; speedup vs baseline: 2.1348x; 1.2017x over previous
//
#include <hip/hip_runtime.h>

#define KC 1024
#define DD 256
#define NROWS 65536
#define BM 128
#define NT 512
#define RESCUE_EPS 0.02f
#define RB 8

typedef _Float16 f16x8 __attribute__((ext_vector_type(8)));
typedef float f32x4 __attribute__((ext_vector_type(4)));
typedef const __attribute__((address_space(1))) unsigned int* gptr_t;
typedef __attribute__((address_space(3))) unsigned int* lptr_t;

__global__ void wprep(const float* __restrict__ W, _Float16* __restrict__ wh,
                      float* __restrict__ se) {
    int k = blockIdx.x, lane = threadIdx.x;
    float4 v = reinterpret_cast<const float4*>(W + (size_t)k * DD)[lane];
    float vv[4] = {v.x, v.y, v.z, v.w};
    _Float16 h4[4];
    double s = 0.0;
#pragma unroll
    for (int q = 0; q < 4; ++q) {
        h4[q] = (_Float16)vv[q];
        s += (double)vv[q] * vv[q];
    }
    *reinterpret_cast<uint2*>(wh + (size_t)k * DD + lane * 4) = *reinterpret_cast<uint2*>(h4);
    for (int m = 32; m >= 1; m >>= 1) s += __shfl_xor(s, m, 64);
    if (lane == 0) se[k] = (float)s;
}

__global__ __launch_bounds__(256) void wtrans4(const float* __restrict__ W,
                                               float4* __restrict__ WT4) {
    __shared__ __align__(16) float4 tile[64][65];
    const int c0 = blockIdx.x * 64;
    const int t = threadIdx.x;
    for (int it = 0; it < 16; ++it) {
        int idx = it * 256 + t;
        int cl = idx >> 6, d4 = idx & 63;
        tile[cl][d4] = reinterpret_cast<const float4*>(W + (size_t)(c0 + cl) * DD)[d4];
    }
    __syncthreads();
    for (int it = 0; it < 16; ++it) {
        int idx = it * 256 + t;
        int d4 = idx >> 6, cl = idx & 63;
        WT4[(size_t)d4 * KC + c0 + cl] = tile[cl][d4];
    }
}

__global__ __launch_bounds__(NT, 2) void vq_mfma(
    const float* __restrict__ X,
    const _Float16* __restrict__ wh,
    const float* __restrict__ se,
    float* __restrict__ out_q, float* __restrict__ out_idx,
    int* __restrict__ idx_int, float* __restrict__ sx_out,
    int* __restrict__ flags, int* __restrict__ count,
    float* __restrict__ counts, double* __restrict__ loss_acc)
{
    __shared__ __align__(16) _Float16 wt[2][64 * 256];
    __shared__ float sxs[BM];
    __shared__ float ses[KC];
    __shared__ int argidx[BM];
    __shared__ double lred[8];

    const int tid = threadIdx.x;
    const int row0 = blockIdx.x * BM;
    const int w = tid >> 6, lane = tid & 63;
    const int m = lane & 15, g = lane >> 4;

    for (int i = tid; i < KC; i += NT) ses[i] = se[i];

    f16x8 ahr[8];
    {
        const float* xr = X + (size_t)(row0 + w * 16 + m) * DD;
        float p0 = 0.f, p1 = 0.f, p2 = 0.f, p3 = 0.f;
#pragma unroll
        for (int ks = 0; ks < 8; ++ks) {
            float4 a = *reinterpret_cast<const float4*>(xr + ks * 32 + g * 8);
            float4 b = *reinterpret_cast<const float4*>(xr + ks * 32 + g * 8 + 4);
            float v[8] = {a.x, a.y, a.z, a.w, b.x, b.y, b.z, b.w};
            f16x8 h;
#pragma unroll
            for (int q = 0; q < 8; ++q) h[q] = (_Float16)v[q];
            ahr[ks] = h;
            p0 = fmaf(v[0], v[0], fmaf(v[4], v[4], p0));
            p1 = fmaf(v[1], v[1], fmaf(v[5], v[5], p1));
            p2 = fmaf(v[2], v[2], fmaf(v[6], v[6], p2));
            p3 = fmaf(v[3], v[3], fmaf(v[7], v[7], p3));
        }
        float ss = (p0 + p1) + (p2 + p3);
        ss += __shfl_xor(ss, 16, 64);
        ss += __shfl_xor(ss, 32, 64);
        if (g == 0) sxs[w * 16 + m] = ss;
    }

    auto stage = [&](int ct, int buf) {
        const int base = ct * 64;
#pragma unroll
        for (int p = 0; p < 4; ++p) {
            int gi = p * NT + tid;
            int code = gi >> 5, j = gi & 31;
            int kq = j ^ (code & 31);
            const _Float16* src = wh + (size_t)(base + code) * DD + kq * 8;
            __builtin_amdgcn_global_load_lds((gptr_t)(const void*)src,
                                             (lptr_t)(void*)&wt[buf][gi * 8], 16, 0, 0);
        }
    };

    stage(0, 0);
    __syncthreads();

    float b1[4], b2[4];
    int i1[4];
#pragma unroll
    for (int j = 0; j < 4; ++j) { b1[j] = 3.4e38f; b2[j] = 3.4e38f; i1[j] = 0; }

    float sxr[4];
#pragma unroll
    for (int j = 0; j < 4; ++j) sxr[j] = sxs[w * 16 + g * 4 + j];

    for (int ct = 0; ct < 16; ++ct) {
        const int buf = ct & 1;
        if (ct < 15) stage(ct + 1, buf ^ 1);

        const _Float16* wtb = wt[buf];
        f32x4 acc[4];
#pragma unroll
        for (int cs = 0; cs < 4; ++cs) acc[cs] = (f32x4){0.f, 0.f, 0.f, 0.f};

#pragma unroll
        for (int ks = 0; ks < 8; ++ks) {
            const int kq = ks * 4 + g;
#pragma unroll
            for (int cs = 0; cs < 4; ++cs) {
                const int code = cs * 16 + m;
                const int L = code * 32 + (kq ^ (code & 31));
                f16x8 bh = *reinterpret_cast<const f16x8*>(wtb + L * 8);
                acc[cs] = __builtin_amdgcn_mfma_f32_16x16x32_f16(ahr[ks], bh, acc[cs], 0, 0, 0);
            }
        }
#pragma unroll
        for (int cs = 0; cs < 4; ++cs) {
            const int code = ct * 64 + cs * 16 + m;
            const float sec = ses[code];
#pragma unroll
            for (int j = 0; j < 4; ++j) {
                float s = __fsub_rn(__fadd_rn(sxr[j], sec), __fmul_rn(2.0f, acc[cs][j]));
                if (s < b1[j]) { b2[j] = b1[j]; b1[j] = s; i1[j] = code; }
                else if (s < b2[j]) { b2[j] = s; }
            }
        }
        __syncthreads();
    }

#pragma unroll
    for (int j = 0; j < 4; ++j) {
        float v1 = b1[j], v2 = b2[j];
        int ix = i1[j];
        for (int mm = 1; mm < 16; mm <<= 1) {
            float ov1 = __shfl_xor(v1, mm, 64);
            int oi = __shfl_xor(ix, mm, 64);
            float ov2 = __shfl_xor(v2, mm, 64);
            float nv2 = fminf(fminf(v2, ov2), fmaxf(v1, ov1));
            if (ov1 < v1 || (ov1 == v1 && oi < ix)) { v1 = ov1; ix = oi; }
            v2 = nv2;
        }
        if (m == 0) {
            int rl = w * 16 + g * 4 + j;
            argidx[rl] = ix;
            if (v2 - v1 < RESCUE_EPS) {
                int p = atomicAdd(count, 1);
                flags[p] = row0 + rl;
            }
        }
    }
    __syncthreads();

    if (tid < BM) {
        int row = row0 + tid;
        int k = argidx[tid];
        idx_int[row] = k;
        out_idx[row] = (float)k;
        sx_out[row] = sxs[tid];
        atomicAdd(&counts[k], 1.0f);
    }

    // register epilogue (fp16 reconstruction; tolerance 20.48)
    {
        double lacc = 0.0;
        const int rl = w * 16 + m;
        const int row = row0 + rl;
        const int k = argidx[rl];
        const _Float16* qh = wh + (size_t)k * DD;
        float* orow = out_q + (size_t)row * DD;
#pragma unroll
        for (int ks = 0; ks < 8; ++ks) {
            const int col = ks * 32 + g * 8;
            union { uint4 u; _Float16 h[8]; } qv, xv;
            qv.u = *reinterpret_cast<const uint4*>(qh + col);
            xv.u = *reinterpret_cast<uint4*>(&ahr[ks]);
            float o8[8];
#pragma unroll
            for (int q = 0; q < 8; ++q) {
                float xf = (float)xv.h[q];
                float qf = (float)qv.h[q];
                float df = qf - xf;
                o8[q] = xf + df;
                lacc += (double)df * df;
            }
            *reinterpret_cast<float4*>(orow + col)     = *reinterpret_cast<float4*>(&o8[0]);
            *reinterpret_cast<float4*>(orow + col + 4) = *reinterpret_cast<float4*>(&o8[4]);
        }
        for (int mm = 32; mm >= 1; mm >>= 1) lacc += __shfl_xor(lacc, mm, 64);
        if (lane == 0) lred[w] = lacc;
    }
    __syncthreads();
    if (tid == 0) {
        double t = 0.0;
        for (int i = 0; i < 8; ++i) t += lred[i];
        atomicAdd(loss_acc, t);
    }
}

// batched rescue: RB=8 rows/block (500 MB L2 W-traffic), exact-fp32 scan
__global__ __launch_bounds__(256) void rescue(
    const float* __restrict__ X, const float4* __restrict__ WT4,
    const float* __restrict__ Wf,
    const float* __restrict__ se, const float* __restrict__ sx,
    const int* __restrict__ flags, const int* __restrict__ count,
    int* __restrict__ idx_int, float* __restrict__ out_idx,
    float* __restrict__ out_q, float* __restrict__ counts,
    double* __restrict__ loss_acc)
{
    __shared__ __align__(16) float xs[RB][DD];
    __shared__ float rv[RB][256];
    __shared__ int ri[RB][256];
    __shared__ float sxr_s[RB];
    __shared__ int rows_s[RB];
    __shared__ int kn_s[RB], ko_s[RB];
    __shared__ double dred[4];
    const int t = threadIdx.x;
    const int n = count[0];

    for (int base = blockIdx.x * RB; base < n; base += gridDim.x * RB) {
        const int nb = min(RB, n - base);
        for (int idx = t; idx < nb * 64; idx += 256) {
            int r = idx >> 6, c4 = idx & 63;
            float4 v = reinterpret_cast<const float4*>(X + (size_t)flags[base + r] * DD)[c4];
            *reinterpret_cast<float4*>(&xs[r][c4 * 4]) = v;
        }
        if (t < nb) { rows_s[t] = flags[base + t]; sxr_s[t] = sx[flags[base + t]]; }
        __syncthreads();

        float acc[4][RB];
#pragma unroll
        for (int cc = 0; cc < 4; ++cc)
#pragma unroll
            for (int r = 0; r < RB; ++r) acc[cc][r] = 0.0f;

        float4 wv[4], wn[4];
#pragma unroll
        for (int cc = 0; cc < 4; ++cc) wv[cc] = WT4[(size_t)0 * KC + cc * 256 + t];

        for (int d4 = 0; d4 < 64; ++d4) {
            const int dn = (d4 < 63) ? d4 + 1 : 63;
#pragma unroll
            for (int cc = 0; cc < 4; ++cc) wn[cc] = WT4[(size_t)dn * KC + cc * 256 + t];
#pragma unroll
            for (int r = 0; r < RB; ++r) {
                float4 xv = *reinterpret_cast<const float4*>(&xs[r][d4 * 4]);
#pragma unroll
                for (int cc = 0; cc < 4; ++cc)
                    acc[cc][r] = fmaf(xv.w, wv[cc].w, fmaf(xv.z, wv[cc].z,
                                 fmaf(xv.y, wv[cc].y, fmaf(xv.x, wv[cc].x, acc[cc][r]))));
            }
#pragma unroll
            for (int cc = 0; cc < 4; ++cc) wv[cc] = wn[cc];
        }

        float best[RB];
        int bidx[RB];
#pragma unroll
        for (int r = 0; r < RB; ++r) { best[r] = 3.4e38f; bidx[r] = 0; }
#pragma unroll
        for (int cc = 0; cc < 4; ++cc) {
            const int c = cc * 256 + t;
            const float sec = se[c];
#pragma unroll
            for (int r = 0; r < RB; ++r) {
                float s = __fsub_rn(__fadd_rn(sxr_s[r], sec), __fmul_rn(2.0f, acc[cc][r]));
                if (s < best[r] || (s == best[r] && c < bidx[r])) { best[r] = s; bidx[r] = c; }
            }
        }
#pragma unroll
        for (int r = 0; r < RB; ++r) { rv[r][t] = best[r]; ri[r][t] = bidx[r]; }
        __syncthreads();

        for (int sft = 128; sft >= 1; sft >>= 1) {
            if (t < sft) {
#pragma unroll
                for (int r = 0; r < RB; ++r) {
                    float ov = rv[r][t + sft];
                    int oi = ri[r][t + sft];
                    if (ov < rv[r][t] || (ov == rv[r][t] && oi < ri[r][t])) {
                        rv[r][t] = ov; ri[r][t] = oi;
                    }
                }
            }
            __syncthreads();
        }
        if (t < nb) {
            int row = rows_s[t];
            int kn = ri[t][0], ko = idx_int[row];
            kn_s[t] = kn; ko_s[t] = ko;
            if (kn != ko) {
                idx_int[row] = kn;
                out_idx[row] = (float)kn;
                atomicAdd(&counts[ko], -1.0f);
                atomicAdd(&counts[kn], 1.0f);
            }
        }
        __syncthreads();

        for (int r = 0; r < nb; ++r) {
            const int ko = ko_s[r], kn = kn_s[r];
            if (kn != ko) {
                const int row = rows_s[r];
                float x = xs[r][t];
                float qo = Wf[(size_t)ko * DD + t];
                float qn = Wf[(size_t)kn * DD + t];
                float dfn = qn - x, dfo = qo - x;
                out_q[(size_t)row * DD + t] = x + dfn;
                double dl = (double)dfn * dfn - (double)dfo * dfo;
                for (int mm = 32; mm >= 1; mm >>= 1) dl += __shfl_xor(dl, mm, 64);
                if ((t & 63) == 0) dred[t >> 6] = dl;
                __syncthreads();
                if (t == 0) atomicAdd(loss_acc, dred[0] + dred[1] + dred[2] + dred[3]);
                __syncthreads();
            }
        }
        __syncthreads();
    }
}

// exclusive prefix over final counts; zero cursors
__global__ void prefix1024(const float* __restrict__ counts, int* __restrict__ off,
                           int* __restrict__ cur) {
    __shared__ int s[1024];
    int t = threadIdx.x;
    s[t] = (int)counts[t];
    __syncthreads();
    for (int d = 1; d < 1024; d <<= 1) {
        int v = (t >= d) ? s[t - d] : 0;
        __syncthreads();
        s[t] += v;
        __syncthreads();
    }
    off[t] = (t == 0) ? 0 : s[t - 1];
    cur[t] = 0;
    if (t == 0) off[1024] = 65536;  // guard (stored in extra slot)
}

// scatter rows into code-sorted order
__global__ __launch_bounds__(256) void scatter_rows(
    const int* __restrict__ idx_int, const int* __restrict__ off,
    int* __restrict__ cur, int* __restrict__ sorted) {
    int i = blockIdx.x * 256 + threadIdx.x;
    int k = idx_int[i];
    int p = atomicAdd(&cur[k], 1);
    sorted[off[k] + p] = i;
}

// gather-sum per code: 4 independent accumulator chains
__global__ __launch_bounds__(256) void emb_gather(
    const float* __restrict__ X, const int* __restrict__ off,
    const int* __restrict__ sorted, float* __restrict__ emb) {
    const int k = blockIdx.x, t = threadIdx.x;
    const int s0 = off[k], s1 = off[k + 1];
    float a0 = 0.f, a1 = 0.f, a2 = 0.f, a3 = 0.f;
    int i = s0;
    for (; i + 4 <= s1; i += 4) {
        int r0 = sorted[i], r1 = sorted[i + 1], r2 = sorted[i + 2], r3 = sorted[i + 3];
        a0 += X[(size_t)r0 * DD + t];
        a1 += X[(size_t)r1 * DD + t];
        a2 += X[(size_t)r2 * DD + t];
        a3 += X[(size_t)r3 * DD + t];
    }
    for (; i < s1; ++i) a0 += X[(size_t)sorted[i] * DD + t];
    emb[(size_t)k * DD + t] = (a0 + a1) + (a2 + a3);
}

__global__ void fin1(const float* __restrict__ ema_cs, float* __restrict__ ncs_buf,
                     const double* __restrict__ loss_acc, float* __restrict__ out_loss,
                     float* __restrict__ n_out)
{
    __shared__ float red[1024];
    int t = threadIdx.x;
    const float OM = (float)(1.0 - 0.99);
    float ncs = __fadd_rn(__fmul_rn(0.99f, ema_cs[t]), __fmul_rn(OM, ncs_buf[t]));
    ncs_buf[t] = ncs;
    red[t] = ncs;
    __syncthreads();
    for (int s = 512; s >= 1; s >>= 1) {
        if (t < s) red[t] += red[t + s];
        __syncthreads();
    }
    if (t == 0) {
        n_out[0] = red[0];
        float el = (float)(loss_acc[0] / 16777216.0);
        out_loss[0] = __fadd_rn(el, __fmul_rn(0.25f, el));
    }
}

__global__ __launch_bounds__(256) void fin2(const float* __restrict__ ema_avg,
                                            float* __restrict__ avg_buf,
                                            const float* __restrict__ ncs,
                                            const float* __restrict__ n_ptr,
                                            float* __restrict__ out_w)
{
    int k = blockIdx.x, d = threadIdx.x;
    const float OM = (float)(1.0 - 0.99);
    const float KEPS = (float)(1024.0 * 1e-5);
    size_t i = (size_t)k * DD + d;
    float avg = __fadd_rn(__fmul_rn(0.99f, ema_avg[i]), __fmul_rn(OM, avg_buf[i]));
    float n = n_ptr[0];
    float cs = __fmul_rn(__fdiv_rn(__fadd_rn(ncs[k], 1e-5f), __fadd_rn(n, KEPS)), n);
    avg_buf[i] = avg;
    out_w[i] = __fdiv_rn(avg, cs);
}

extern "C" void kernel_launch(void* const* d_in, const int* in_sizes, int n_in,
                              void* d_out, int out_size, void* d_ws, size_t ws_size,
                              hipStream_t stream) {
    const float* X = (const float*)d_in[0];
    const float* W = (const float*)d_in[1];
    const float* ema_cs = (const float*)d_in[2];
    const float* ema_avg = (const float*)d_in[3];

    float* out = (float*)d_out;
    float* out_q    = out;
    float* out_loss = out + 16777216;
    float* out_idx  = out + 16777217;
    float* out_w    = out + 16842753;
    float* out_ncs  = out + 17104897;
    float* out_avg  = out + 17105921;

    char* ws = (char*)d_ws;
    float* se      = (float*)(ws + 0);
    float* n_ptr   = (float*)(ws + 4096);
    double* loss   = (double*)(ws + 4112);
    int*   count   = (int*)(ws + 4128);
    _Float16* wh   = (_Float16*)(ws + 8192);
    float* sx      = (float*)(ws + 1056768);
    int*   idx_int = (int*)(ws + 1318912);
    int*   flags   = (int*)(ws + 1581056);
    float4* WT4    = (float4*)(ws + 2097152);
    int*   off     = (int*)(ws + 3145728);       // 1025 ints
    int*   cur     = (int*)(ws + 3153920);       // 1024 ints
    int*   sorted  = (int*)(ws + 3158016);       // 65536 ints

    hipMemsetAsync(out_ncs, 0, 1024 * sizeof(float), stream);
    hipMemsetAsync(loss, 0, sizeof(double), stream);
    hipMemsetAsync(count, 0, sizeof(int), stream);

    wprep<<<KC, 64, 0, stream>>>(W, wh, se);
    wtrans4<<<16, 256, 0, stream>>>(W, WT4);
    vq_mfma<<<NROWS / BM, NT, 0, stream>>>(X, wh, se, out_q, out_idx,
                                           idx_int, sx, flags, count,
                                           out_ncs, loss);
    rescue<<<512, 256, 0, stream>>>(X, WT4, W, se, sx, flags, count, idx_int, out_idx,
                                    out_q, out_ncs, loss);
    prefix1024<<<1, 1024, 0, stream>>>(out_ncs, off, cur);
    scatter_rows<<<NROWS / 256, 256, 0, stream>>>(idx_int, off, cur, sorted);
    emb_gather<<<KC, 256, 0, stream>>>(X, off, sorted, out_avg);
    fin1<<<1, 1024, 0, stream>>>(ema_cs, out_ncs, loss, out_loss, n_ptr);
    fin2<<<KC, 256, 0, stream>>>(ema_avg, out_avg, out_ncs, n_ptr, out_w);
}

// Round 24
// 183.680 us; speedup vs baseline: 2.1954x; 1.0284x over previous
//
#include <hip/hip_runtime.h>

#define KC 1024
#define DD 256
#define NROWS 65536
#define BM 128
#define NT 512
#define RESCUE_EPS 0.02f
#define RB 8

typedef _Float16 f16x8 __attribute__((ext_vector_type(8)));
typedef __fp16 fp16x2 __attribute__((ext_vector_type(2)));
typedef float f32x4 __attribute__((ext_vector_type(4)));
typedef const __attribute__((address_space(1))) unsigned int* gptr_t;
typedef __attribute__((address_space(3))) unsigned int* lptr_t;

// W -> fp16 (pkrtz) + |e_k|^2 + WT4 (transposed float4 planes)
__global__ void wprep(const float* __restrict__ W, _Float16* __restrict__ wh,
                      float* __restrict__ se, float4* __restrict__ WT4) {
    int k = blockIdx.x, lane = threadIdx.x;
    float4 v = reinterpret_cast<const float4*>(W + (size_t)k * DD)[lane];
    union { fp16x2 h2[2]; uint2 u; } cv;
    cv.h2[0] = __builtin_amdgcn_cvt_pkrtz(v.x, v.y);
    cv.h2[1] = __builtin_amdgcn_cvt_pkrtz(v.z, v.w);
    *reinterpret_cast<uint2*>(wh + (size_t)k * DD + lane * 4) = cv.u;
    WT4[(size_t)lane * KC + k] = v;
    double s = (double)v.x * v.x + (double)v.y * v.y + (double)v.z * v.z + (double)v.w * v.w;
    for (int m = 32; m >= 1; m >>= 1) s += __shfl_xor(s, m, 64);
    if (lane == 0) se[k] = (float)s;
}

__global__ __launch_bounds__(NT, 2) void vq_mfma(
    const float* __restrict__ X,
    const _Float16* __restrict__ wh,
    const float* __restrict__ se,
    float* __restrict__ out_q, float* __restrict__ out_idx,
    int* __restrict__ idx_int, float* __restrict__ sx_out,
    int* __restrict__ flags, int* __restrict__ count,
    float* __restrict__ counts, double* __restrict__ loss_acc)
{
    __shared__ __align__(16) _Float16 wt[2][64 * 256];
    __shared__ float sxs[BM];
    __shared__ float ses[KC];
    __shared__ int argidx[BM];
    __shared__ double lred[8];

    const int tid = threadIdx.x;
    const int row0 = blockIdx.x * BM;
    const int w = tid >> 6, lane = tid & 63;
    const int m = lane & 15, g = lane >> 4;

    for (int i = tid; i < KC; i += NT) ses[i] = se[i];

    f16x8 ahr[8];
    {
        const float* xr = X + (size_t)(row0 + w * 16 + m) * DD;
        float p0 = 0.f, p1 = 0.f, p2 = 0.f, p3 = 0.f;
#pragma unroll
        for (int ks = 0; ks < 8; ++ks) {
            float4 a = *reinterpret_cast<const float4*>(xr + ks * 32 + g * 8);
            float4 b = *reinterpret_cast<const float4*>(xr + ks * 32 + g * 8 + 4);
            union { fp16x2 h2[4]; f16x8 h8; } cv;
            cv.h2[0] = __builtin_amdgcn_cvt_pkrtz(a.x, a.y);
            cv.h2[1] = __builtin_amdgcn_cvt_pkrtz(a.z, a.w);
            cv.h2[2] = __builtin_amdgcn_cvt_pkrtz(b.x, b.y);
            cv.h2[3] = __builtin_amdgcn_cvt_pkrtz(b.z, b.w);
            ahr[ks] = cv.h8;
            p0 = fmaf(a.x, a.x, fmaf(b.x, b.x, p0));
            p1 = fmaf(a.y, a.y, fmaf(b.y, b.y, p1));
            p2 = fmaf(a.z, a.z, fmaf(b.z, b.z, p2));
            p3 = fmaf(a.w, a.w, fmaf(b.w, b.w, p3));
        }
        float ss = (p0 + p1) + (p2 + p3);
        ss += __shfl_xor(ss, 16, 64);
        ss += __shfl_xor(ss, 32, 64);
        if (g == 0) sxs[w * 16 + m] = ss;
    }

    size_t srcoff[4];
    unsigned ldsoff[4];
#pragma unroll
    for (int p = 0; p < 4; ++p) {
        int gi = p * NT + tid;
        int code = gi >> 5, j = gi & 31;
        int kq = j ^ (code & 31);
        srcoff[p] = (size_t)code * DD + kq * 8;
        ldsoff[p] = gi * 8;
    }
    auto stage = [&](int ct, int buf) {
        const _Float16* b = wh + (size_t)ct * 64 * DD;
#pragma unroll
        for (int p = 0; p < 4; ++p)
            __builtin_amdgcn_global_load_lds((gptr_t)(const void*)(b + srcoff[p]),
                                             (lptr_t)(void*)&wt[buf][ldsoff[p]], 16, 0, 0);
    };

    stage(0, 0);
    __syncthreads();

    float b1[4], b2[4];
    int i1[4];
#pragma unroll
    for (int j = 0; j < 4; ++j) { b1[j] = 3.4e38f; b2[j] = 3.4e38f; i1[j] = 0; }

    float sxr[4];
#pragma unroll
    for (int j = 0; j < 4; ++j) sxr[j] = sxs[w * 16 + g * 4 + j];

    for (int ct = 0; ct < 16; ++ct) {
        const int buf = ct & 1;
        if (ct < 15) stage(ct + 1, buf ^ 1);

        const _Float16* wtb = wt[buf];
        f32x4 acc[4];
#pragma unroll
        for (int cs = 0; cs < 4; ++cs) acc[cs] = (f32x4){0.f, 0.f, 0.f, 0.f};

#pragma unroll
        for (int ks = 0; ks < 8; ++ks) {
            const int kq = ks * 4 + g;
#pragma unroll
            for (int cs = 0; cs < 4; ++cs) {
                const int code = cs * 16 + m;
                const int L = code * 32 + (kq ^ (code & 31));
                f16x8 bh = *reinterpret_cast<const f16x8*>(wtb + L * 8);
                acc[cs] = __builtin_amdgcn_mfma_f32_16x16x32_f16(ahr[ks], bh, acc[cs], 0, 0, 0);
            }
        }
#pragma unroll
        for (int cs = 0; cs < 4; ++cs) {
            const int code = ct * 64 + cs * 16 + m;
            const float sec = ses[code];
#pragma unroll
            for (int j = 0; j < 4; ++j) {
                float s = fmaf(-2.0f, acc[cs][j], sxr[j] + sec);
                if (s < b1[j]) { b2[j] = b1[j]; b1[j] = s; i1[j] = code; }
                else if (s < b2[j]) { b2[j] = s; }
            }
        }
        __syncthreads();
    }

#pragma unroll
    for (int j = 0; j < 4; ++j) {
        float v1 = b1[j], v2 = b2[j];
        int ix = i1[j];
        for (int mm = 1; mm < 16; mm <<= 1) {
            float ov1 = __shfl_xor(v1, mm, 64);
            int oi = __shfl_xor(ix, mm, 64);
            float ov2 = __shfl_xor(v2, mm, 64);
            float nv2 = fminf(fminf(v2, ov2), fmaxf(v1, ov1));
            if (ov1 < v1 || (ov1 == v1 && oi < ix)) { v1 = ov1; ix = oi; }
            v2 = nv2;
        }
        if (m == 0) {
            int rl = w * 16 + g * 4 + j;
            argidx[rl] = ix;
            if (v2 - v1 < RESCUE_EPS) {
                int p = atomicAdd(count, 1);
                flags[p] = row0 + rl;
            }
        }
    }
    __syncthreads();

    if (tid < BM) {
        int row = row0 + tid;
        int k = argidx[tid];
        idx_int[row] = k;
        out_idx[row] = (float)k;
        sx_out[row] = sxs[tid];
        atomicAdd(&counts[k], 1.0f);
    }

    // register epilogue: out_q = (float)q; fp32 loss accumulation
    {
        float lacc = 0.0f;
        const int rl = w * 16 + m;
        const int row = row0 + rl;
        const int k = argidx[rl];
        const _Float16* qh = wh + (size_t)k * DD;
        float* orow = out_q + (size_t)row * DD;
#pragma unroll
        for (int ks = 0; ks < 8; ++ks) {
            const int col = ks * 32 + g * 8;
            union { uint4 u; _Float16 h[8]; } qv, xv;
            qv.u = *reinterpret_cast<const uint4*>(qh + col);
            xv.u = *reinterpret_cast<uint4*>(&ahr[ks]);
            float o8[8];
#pragma unroll
            for (int q = 0; q < 8; ++q) {
                float qf = (float)qv.h[q];
                float df = qf - (float)xv.h[q];
                o8[q] = qf;
                lacc = fmaf(df, df, lacc);
            }
            *reinterpret_cast<float4*>(orow + col)     = *reinterpret_cast<float4*>(&o8[0]);
            *reinterpret_cast<float4*>(orow + col + 4) = *reinterpret_cast<float4*>(&o8[4]);
        }
        for (int mm = 32; mm >= 1; mm >>= 1) lacc += __shfl_xor(lacc, mm, 64);
        if (lane == 0) lred[w] = (double)lacc;
    }
    __syncthreads();
    if (tid == 0) {
        double t = 0.0;
        for (int i = 0; i < 8; ++i) t += lred[i];
        atomicAdd(loss_acc, t);
    }
}

__global__ __launch_bounds__(256) void rescue(
    const float* __restrict__ X, const float4* __restrict__ WT4,
    const float* __restrict__ Wf,
    const float* __restrict__ se, const float* __restrict__ sx,
    const int* __restrict__ flags, const int* __restrict__ count,
    int* __restrict__ idx_int, float* __restrict__ out_idx,
    float* __restrict__ out_q, float* __restrict__ counts,
    double* __restrict__ loss_acc)
{
    __shared__ __align__(16) float xs[RB][DD];
    __shared__ float rv[RB][256];
    __shared__ int ri[RB][256];
    __shared__ float sxr_s[RB];
    __shared__ int rows_s[RB];
    __shared__ int kn_s[RB], ko_s[RB];
    __shared__ double dred[4];
    const int t = threadIdx.x;
    const int n = count[0];

    for (int base = blockIdx.x * RB; base < n; base += gridDim.x * RB) {
        const int nb = min(RB, n - base);
        for (int idx = t; idx < nb * 64; idx += 256) {
            int r = idx >> 6, c4 = idx & 63;
            float4 v = reinterpret_cast<const float4*>(X + (size_t)flags[base + r] * DD)[c4];
            *reinterpret_cast<float4*>(&xs[r][c4 * 4]) = v;
        }
        if (t < nb) { rows_s[t] = flags[base + t]; sxr_s[t] = sx[flags[base + t]]; }
        __syncthreads();

        float acc[4][RB];
#pragma unroll
        for (int cc = 0; cc < 4; ++cc)
#pragma unroll
            for (int r = 0; r < RB; ++r) acc[cc][r] = 0.0f;

        float4 wv[4], wn[4];
#pragma unroll
        for (int cc = 0; cc < 4; ++cc) wv[cc] = WT4[(size_t)0 * KC + cc * 256 + t];

        for (int d4 = 0; d4 < 64; ++d4) {
            const int dn = (d4 < 63) ? d4 + 1 : 63;
#pragma unroll
            for (int cc = 0; cc < 4; ++cc) wn[cc] = WT4[(size_t)dn * KC + cc * 256 + t];
#pragma unroll
            for (int r = 0; r < RB; ++r) {
                float4 xv = *reinterpret_cast<const float4*>(&xs[r][d4 * 4]);
#pragma unroll
                for (int cc = 0; cc < 4; ++cc)
                    acc[cc][r] = fmaf(xv.w, wv[cc].w, fmaf(xv.z, wv[cc].z,
                                 fmaf(xv.y, wv[cc].y, fmaf(xv.x, wv[cc].x, acc[cc][r]))));
            }
#pragma unroll
            for (int cc = 0; cc < 4; ++cc) wv[cc] = wn[cc];
        }

        float best[RB];
        int bidx[RB];
#pragma unroll
        for (int r = 0; r < RB; ++r) { best[r] = 3.4e38f; bidx[r] = 0; }
#pragma unroll
        for (int cc = 0; cc < 4; ++cc) {
            const int c = cc * 256 + t;
            const float sec = se[c];
#pragma unroll
            for (int r = 0; r < RB; ++r) {
                float s = __fsub_rn(__fadd_rn(sxr_s[r], sec), __fmul_rn(2.0f, acc[cc][r]));
                if (s < best[r] || (s == best[r] && c < bidx[r])) { best[r] = s; bidx[r] = c; }
            }
        }
#pragma unroll
        for (int r = 0; r < RB; ++r) { rv[r][t] = best[r]; ri[r][t] = bidx[r]; }
        __syncthreads();

        for (int sft = 128; sft >= 1; sft >>= 1) {
            if (t < sft) {
#pragma unroll
                for (int r = 0; r < RB; ++r) {
                    float ov = rv[r][t + sft];
                    int oi = ri[r][t + sft];
                    if (ov < rv[r][t] || (ov == rv[r][t] && oi < ri[r][t])) {
                        rv[r][t] = ov; ri[r][t] = oi;
                    }
                }
            }
            __syncthreads();
        }
        if (t < nb) {
            int row = rows_s[t];
            int kn = ri[t][0], ko = idx_int[row];
            kn_s[t] = kn; ko_s[t] = ko;
            if (kn != ko) {
                idx_int[row] = kn;
                out_idx[row] = (float)kn;
                atomicAdd(&counts[ko], -1.0f);
                atomicAdd(&counts[kn], 1.0f);
            }
        }
        __syncthreads();

        for (int r = 0; r < nb; ++r) {
            const int ko = ko_s[r], kn = kn_s[r];
            if (kn != ko) {
                const int row = rows_s[r];
                float x = xs[r][t];
                float qo = Wf[(size_t)ko * DD + t];
                float qn = Wf[(size_t)kn * DD + t];
                float dfn = qn - x, dfo = qo - x;
                out_q[(size_t)row * DD + t] = x + dfn;
                double dl = (double)dfn * dfn - (double)dfo * dfo;
                for (int mm = 32; mm >= 1; mm >>= 1) dl += __shfl_xor(dl, mm, 64);
                if ((t & 63) == 0) dred[t >> 6] = dl;
                __syncthreads();
                if (t == 0) atomicAdd(loss_acc, dred[0] + dred[1] + dred[2] + dred[3]);
                __syncthreads();
            }
        }
        __syncthreads();
    }
}

__global__ void finprefix(const float* __restrict__ ema_cs, float* __restrict__ ncs_buf,
                          const double* __restrict__ loss_acc, float* __restrict__ out_loss,
                          float* __restrict__ n_out, int* __restrict__ off,
                          int* __restrict__ cur)
{
    __shared__ float red[1024];
    __shared__ int s[1024];
    int t = threadIdx.x;
    const float OM = (float)(1.0 - 0.99);
    float cnt = ncs_buf[t];
    s[t] = (int)cnt;
    float ncs = __fadd_rn(__fmul_rn(0.99f, ema_cs[t]), __fmul_rn(OM, cnt));
    ncs_buf[t] = ncs;
    red[t] = ncs;
    __syncthreads();
    for (int st = 512; st >= 1; st >>= 1) {
        if (t < st) red[t] += red[t + st];
        __syncthreads();
    }
    if (t == 0) {
        n_out[0] = red[0];
        float el = (float)(loss_acc[0] / 16777216.0);
        out_loss[0] = __fadd_rn(el, __fmul_rn(0.25f, el));
    }
    for (int d = 1; d < 1024; d <<= 1) {
        int v = (t >= d) ? s[t - d] : 0;
        __syncthreads();
        s[t] += v;
        __syncthreads();
    }
    off[t] = (t == 0) ? 0 : s[t - 1];
    cur[t] = 0;
    if (t == 0) off[1024] = NROWS;
}

__global__ __launch_bounds__(256) void scatter_rows(
    const int* __restrict__ idx_int, const int* __restrict__ off,
    int* __restrict__ cur, int* __restrict__ sorted) {
    int i = blockIdx.x * 256 + threadIdx.x;
    int k = idx_int[i];
    int p = atomicAdd(&cur[k], 1);
    sorted[off[k] + p] = i;
}

__global__ __launch_bounds__(256) void embfin2(
    const float* __restrict__ X, const int* __restrict__ off,
    const int* __restrict__ sorted, const float* __restrict__ ema_avg,
    const float* __restrict__ ncs, const float* __restrict__ n_ptr,
    float* __restrict__ out_avg, float* __restrict__ out_w)
{
    const int k = blockIdx.x, t = threadIdx.x;
    const int s0 = off[k], s1 = off[k + 1];
    float a0 = 0.f, a1 = 0.f, a2 = 0.f, a3 = 0.f;
    int i = s0;
    for (; i + 4 <= s1; i += 4) {
        int r0 = sorted[i], r1 = sorted[i + 1], r2 = sorted[i + 2], r3 = sorted[i + 3];
        a0 += X[(size_t)r0 * DD + t];
        a1 += X[(size_t)r1 * DD + t];
        a2 += X[(size_t)r2 * DD + t];
        a3 += X[(size_t)r3 * DD + t];
    }
    for (; i < s1; ++i) a0 += X[(size_t)sorted[i] * DD + t];
    float total = (a0 + a1) + (a2 + a3);

    const float OM = (float)(1.0 - 0.99);
    const float KEPS = (float)(1024.0 * 1e-5);
    size_t o = (size_t)k * DD + t;
    float avg = __fadd_rn(__fmul_rn(0.99f, ema_avg[o]), __fmul_rn(OM, total));
    float n = n_ptr[0];
    float cs = __fmul_rn(__fdiv_rn(__fadd_rn(ncs[k], 1e-5f), __fadd_rn(n, KEPS)), n);
    out_avg[o] = avg;
    out_w[o] = __fdiv_rn(avg, cs);
}

extern "C" void kernel_launch(void* const* d_in, const int* in_sizes, int n_in,
                              void* d_out, int out_size, void* d_ws, size_t ws_size,
                              hipStream_t stream) {
    const float* X = (const float*)d_in[0];
    const float* W = (const float*)d_in[1];
    const float* ema_cs = (const float*)d_in[2];
    const float* ema_avg = (const float*)d_in[3];

    float* out = (float*)d_out;
    float* out_q    = out;
    float* out_loss = out + 16777216;
    float* out_idx  = out + 16777217;
    float* out_w    = out + 16842753;
    float* out_ncs  = out + 17104897;
    float* out_avg  = out + 17105921;

    char* ws = (char*)d_ws;
    float* se      = (float*)(ws + 0);
    float* n_ptr   = (float*)(ws + 4096);
    double* loss   = (double*)(ws + 4112);
    int*   count   = (int*)(ws + 4128);
    _Float16* wh   = (_Float16*)(ws + 8192);
    float* sx      = (float*)(ws + 1056768);
    int*   idx_int = (int*)(ws + 1318912);
    int*   flags   = (int*)(ws + 1581056);
    float4* WT4    = (float4*)(ws + 2097152);
    int*   off     = (int*)(ws + 3145728);
    int*   cur     = (int*)(ws + 3153920);
    int*   sorted  = (int*)(ws + 3158016);

    hipMemsetAsync(out_ncs, 0, 1024 * sizeof(float), stream);
    hipMemsetAsync(loss, 0, sizeof(double), stream);
    hipMemsetAsync(count, 0, sizeof(int), stream);

    wprep<<<KC, 64, 0, stream>>>(W, wh, se, WT4);
    vq_mfma<<<NROWS / BM, NT, 0, stream>>>(X, wh, se, out_q, out_idx,
                                           idx_int, sx, flags, count,
                                           out_ncs, loss);
    rescue<<<512, 256, 0, stream>>>(X, WT4, W, se, sx, flags, count, idx_int, out_idx,
                                    out_q, out_ncs, loss);
    finprefix<<<1, 1024, 0, stream>>>(ema_cs, out_ncs, loss, out_loss, n_ptr, off, cur);
    scatter_rows<<<NROWS / 256, 256, 0, stream>>>(idx_int, off, cur, sorted);
    embfin2<<<KC, 256, 0, stream>>>(X, off, sorted, ema_avg, out_ncs, n_ptr,
                                    out_avg, out_w);
}

// Round 25
// 175.828 us; speedup vs baseline: 2.2935x; 1.0447x over previous
//
#include <hip/hip_runtime.h>

#define KC 1024
#define DD 256
#define NROWS 65536
#define BM 128
#define NT 256
#define RESCUE_EPS 0.02f
#define RB 8

typedef _Float16 f16x8 __attribute__((ext_vector_type(8)));
typedef __fp16 fp16x2 __attribute__((ext_vector_type(2)));
typedef float f32x4 __attribute__((ext_vector_type(4)));
typedef const __attribute__((address_space(1))) unsigned int* gptr_t;
typedef __attribute__((address_space(3))) unsigned int* lptr_t;

// W -> fp16 (pkrtz) + |e_k|^2 + WT4; also zeroes counts/loss/flagcount
__global__ void wprep(const float* __restrict__ W, _Float16* __restrict__ wh,
                      float* __restrict__ se, float4* __restrict__ WT4,
                      float* __restrict__ counts, double* __restrict__ loss,
                      int* __restrict__ flagcnt) {
    int k = blockIdx.x, lane = threadIdx.x;
    float4 v = reinterpret_cast<const float4*>(W + (size_t)k * DD)[lane];
    union { fp16x2 h2[2]; uint2 u; } cv;
    cv.h2[0] = __builtin_amdgcn_cvt_pkrtz(v.x, v.y);
    cv.h2[1] = __builtin_amdgcn_cvt_pkrtz(v.z, v.w);
    *reinterpret_cast<uint2*>(wh + (size_t)k * DD + lane * 4) = cv.u;
    WT4[(size_t)lane * KC + k] = v;
    double s = (double)v.x * v.x + (double)v.y * v.y + (double)v.z * v.z + (double)v.w * v.w;
    for (int m = 32; m >= 1; m >>= 1) s += __shfl_xor(s, m, 64);
    if (lane == 0) {
        se[k] = (float)s;
        counts[k] = 0.0f;
        if (k == 0) { loss[0] = 0.0; flagcnt[0] = 0; }
    }
}

__global__ __launch_bounds__(NT, 2) void vq_mfma(
    const float* __restrict__ X,
    const _Float16* __restrict__ wh,
    const float* __restrict__ se,
    float* __restrict__ out_q, float* __restrict__ out_idx,
    int* __restrict__ idx_int, float* __restrict__ sx_out,
    int* __restrict__ flags, int* __restrict__ count,
    float* __restrict__ counts, double* __restrict__ loss_acc)
{
    __shared__ __align__(16) _Float16 wt[2][64 * 256];  // 64 KB
    __shared__ float sxs[BM];
    __shared__ float ses[KC];
    __shared__ int argidx[BM];
    __shared__ double lred[4];

    const int tid = threadIdx.x;
    const int row0 = blockIdx.x * BM;
    const int w = tid >> 6, lane = tid & 63;   // 4 waves, wave owns rows w*32..w*32+31
    const int m = lane & 15, g = lane >> 4;

    for (int i = tid; i < KC; i += NT) ses[i] = se[i];

    f16x8 ahr[2][8];
#pragma unroll
    for (int rt = 0; rt < 2; ++rt) {
        const float* xr = X + (size_t)(row0 + w * 32 + rt * 16 + m) * DD;
        float p0 = 0.f, p1 = 0.f, p2 = 0.f, p3 = 0.f;
#pragma unroll
        for (int ks = 0; ks < 8; ++ks) {
            float4 a = *reinterpret_cast<const float4*>(xr + ks * 32 + g * 8);
            float4 b = *reinterpret_cast<const float4*>(xr + ks * 32 + g * 8 + 4);
            union { fp16x2 h2[4]; f16x8 h8; } cv;
            cv.h2[0] = __builtin_amdgcn_cvt_pkrtz(a.x, a.y);
            cv.h2[1] = __builtin_amdgcn_cvt_pkrtz(a.z, a.w);
            cv.h2[2] = __builtin_amdgcn_cvt_pkrtz(b.x, b.y);
            cv.h2[3] = __builtin_amdgcn_cvt_pkrtz(b.z, b.w);
            ahr[rt][ks] = cv.h8;
            p0 = fmaf(a.x, a.x, fmaf(b.x, b.x, p0));
            p1 = fmaf(a.y, a.y, fmaf(b.y, b.y, p1));
            p2 = fmaf(a.z, a.z, fmaf(b.z, b.z, p2));
            p3 = fmaf(a.w, a.w, fmaf(b.w, b.w, p3));
        }
        float ss = (p0 + p1) + (p2 + p3);
        ss += __shfl_xor(ss, 16, 64);
        ss += __shfl_xor(ss, 32, 64);
        if (g == 0) sxs[w * 32 + rt * 16 + m] = ss;
    }

    // 8 granules per thread (2048 granules / 256 threads)
    unsigned srcoff[8], ldsoff[8];
#pragma unroll
    for (int p = 0; p < 8; ++p) {
        int gi = p * NT + tid;
        int code = gi >> 5, j = gi & 31;
        int kq = j ^ (code & 31);
        srcoff[p] = (unsigned)(code * DD + kq * 8);
        ldsoff[p] = gi * 8;
    }
    auto stage = [&](int ct, int buf) {
        const _Float16* b = wh + (size_t)ct * 64 * DD;
#pragma unroll
        for (int p = 0; p < 8; ++p)
            __builtin_amdgcn_global_load_lds((gptr_t)(const void*)(b + srcoff[p]),
                                             (lptr_t)(void*)&wt[buf][ldsoff[p]], 16, 0, 0);
    };

    stage(0, 0);
    __syncthreads();

    float b1[2][4], b2[2][4];
    int i1[2][4];
#pragma unroll
    for (int rt = 0; rt < 2; ++rt)
#pragma unroll
        for (int j = 0; j < 4; ++j) { b1[rt][j] = 3.4e38f; b2[rt][j] = 3.4e38f; i1[rt][j] = 0; }

    float sxr[2][4];
#pragma unroll
    for (int rt = 0; rt < 2; ++rt)
#pragma unroll
        for (int j = 0; j < 4; ++j) sxr[rt][j] = sxs[w * 32 + rt * 16 + g * 4 + j];

    for (int ct = 0; ct < 16; ++ct) {
        const int buf = ct & 1;
        if (ct < 15) stage(ct + 1, buf ^ 1);

        const _Float16* wtb = wt[buf];
        f32x4 acc0[4], acc1[4];
#pragma unroll
        for (int cs = 0; cs < 4; ++cs) {
            acc0[cs] = (f32x4){0.f, 0.f, 0.f, 0.f};
            acc1[cs] = (f32x4){0.f, 0.f, 0.f, 0.f};
        }

#pragma unroll
        for (int ks = 0; ks < 8; ++ks) {
            const int kq = ks * 4 + g;
#pragma unroll
            for (int cs = 0; cs < 4; ++cs) {
                const int code = cs * 16 + m;
                const int L = code * 32 + (kq ^ (code & 31));
                f16x8 bh = *reinterpret_cast<const f16x8*>(wtb + L * 8);
                acc0[cs] = __builtin_amdgcn_mfma_f32_16x16x32_f16(ahr[0][ks], bh, acc0[cs], 0, 0, 0);
                acc1[cs] = __builtin_amdgcn_mfma_f32_16x16x32_f16(ahr[1][ks], bh, acc1[cs], 0, 0, 0);
            }
        }
#pragma unroll
        for (int cs = 0; cs < 4; ++cs) {
            const int code = ct * 64 + cs * 16 + m;
            const float sec = ses[code];
#pragma unroll
            for (int rt = 0; rt < 2; ++rt) {
                f32x4 A = rt ? acc1[cs] : acc0[cs];
#pragma unroll
                for (int j = 0; j < 4; ++j) {
                    float s = fmaf(-2.0f, A[j], sxr[rt][j] + sec);
                    if (s < b1[rt][j]) { b2[rt][j] = b1[rt][j]; b1[rt][j] = s; i1[rt][j] = code; }
                    else if (s < b2[rt][j]) { b2[rt][j] = s; }
                }
            }
        }
        __syncthreads();
    }

#pragma unroll
    for (int rt = 0; rt < 2; ++rt)
#pragma unroll
        for (int j = 0; j < 4; ++j) {
            float v1 = b1[rt][j], v2 = b2[rt][j];
            int ix = i1[rt][j];
            for (int mm = 1; mm < 16; mm <<= 1) {
                float ov1 = __shfl_xor(v1, mm, 64);
                int oi = __shfl_xor(ix, mm, 64);
                float ov2 = __shfl_xor(v2, mm, 64);
                float nv2 = fminf(fminf(v2, ov2), fmaxf(v1, ov1));
                if (ov1 < v1 || (ov1 == v1 && oi < ix)) { v1 = ov1; ix = oi; }
                v2 = nv2;
            }
            if (m == 0) {
                int rl = w * 32 + rt * 16 + g * 4 + j;
                argidx[rl] = ix;
                if (v2 - v1 < RESCUE_EPS) {
                    int p = atomicAdd(count, 1);
                    flags[p] = row0 + rl;
                }
            }
        }
    __syncthreads();

    if (tid < BM) {
        int row = row0 + tid;
        int k = argidx[tid];
        idx_int[row] = k;
        out_idx[row] = (float)k;
        sx_out[row] = sxs[tid];
        atomicAdd(&counts[k], 1.0f);
    }

    // register epilogue: out_q = (float)q; fp32 loss
    {
        float lacc = 0.0f;
#pragma unroll
        for (int rt = 0; rt < 2; ++rt) {
            const int rl = w * 32 + rt * 16 + m;
            const int row = row0 + rl;
            const int k = argidx[rl];
            const _Float16* qh = wh + (size_t)k * DD;
            float* orow = out_q + (size_t)row * DD;
#pragma unroll
            for (int ks = 0; ks < 8; ++ks) {
                const int col = ks * 32 + g * 8;
                union { uint4 u; _Float16 h[8]; } qv, xv;
                qv.u = *reinterpret_cast<const uint4*>(qh + col);
                xv.u = *reinterpret_cast<uint4*>(&ahr[rt][ks]);
                float o8[8];
#pragma unroll
                for (int q = 0; q < 8; ++q) {
                    float qf = (float)qv.h[q];
                    float df = qf - (float)xv.h[q];
                    o8[q] = qf;
                    lacc = fmaf(df, df, lacc);
                }
                *reinterpret_cast<float4*>(orow + col)     = *reinterpret_cast<float4*>(&o8[0]);
                *reinterpret_cast<float4*>(orow + col + 4) = *reinterpret_cast<float4*>(&o8[4]);
            }
        }
        for (int mm = 32; mm >= 1; mm >>= 1) lacc += __shfl_xor(lacc, mm, 64);
        if (lane == 0) lred[w] = (double)lacc;
    }
    __syncthreads();
    if (tid == 0) {
        double t = lred[0] + lred[1] + lred[2] + lred[3];
        atomicAdd(loss_acc, t);
    }
}

__global__ __launch_bounds__(256) void rescue(
    const float* __restrict__ X, const float4* __restrict__ WT4,
    const float* __restrict__ Wf,
    const float* __restrict__ se, const float* __restrict__ sx,
    const int* __restrict__ flags, const int* __restrict__ count,
    int* __restrict__ idx_int, float* __restrict__ out_idx,
    float* __restrict__ out_q, float* __restrict__ counts,
    double* __restrict__ loss_acc)
{
    __shared__ __align__(16) float xs[RB][DD];
    __shared__ float rv[RB][256];
    __shared__ int ri[RB][256];
    __shared__ float sxr_s[RB];
    __shared__ int rows_s[RB];
    __shared__ int kn_s[RB], ko_s[RB];
    __shared__ double dred[4];
    const int t = threadIdx.x;
    const int n = count[0];

    for (int base = blockIdx.x * RB; base < n; base += gridDim.x * RB) {
        const int nb = min(RB, n - base);
        for (int idx = t; idx < nb * 64; idx += 256) {
            int r = idx >> 6, c4 = idx & 63;
            float4 v = reinterpret_cast<const float4*>(X + (size_t)flags[base + r] * DD)[c4];
            *reinterpret_cast<float4*>(&xs[r][c4 * 4]) = v;
        }
        if (t < nb) { rows_s[t] = flags[base + t]; sxr_s[t] = sx[flags[base + t]]; }
        __syncthreads();

        float acc[4][RB];
#pragma unroll
        for (int cc = 0; cc < 4; ++cc)
#pragma unroll
            for (int r = 0; r < RB; ++r) acc[cc][r] = 0.0f;

        float4 wv[4], wn[4];
#pragma unroll
        for (int cc = 0; cc < 4; ++cc) wv[cc] = WT4[(size_t)0 * KC + cc * 256 + t];

        for (int d4 = 0; d4 < 64; ++d4) {
            const int dn = (d4 < 63) ? d4 + 1 : 63;
#pragma unroll
            for (int cc = 0; cc < 4; ++cc) wn[cc] = WT4[(size_t)dn * KC + cc * 256 + t];
#pragma unroll
            for (int r = 0; r < RB; ++r) {
                float4 xv = *reinterpret_cast<const float4*>(&xs[r][d4 * 4]);
#pragma unroll
                for (int cc = 0; cc < 4; ++cc)
                    acc[cc][r] = fmaf(xv.w, wv[cc].w, fmaf(xv.z, wv[cc].z,
                                 fmaf(xv.y, wv[cc].y, fmaf(xv.x, wv[cc].x, acc[cc][r]))));
            }
#pragma unroll
            for (int cc = 0; cc < 4; ++cc) wv[cc] = wn[cc];
        }

        float best[RB];
        int bidx[RB];
#pragma unroll
        for (int r = 0; r < RB; ++r) { best[r] = 3.4e38f; bidx[r] = 0; }
#pragma unroll
        for (int cc = 0; cc < 4; ++cc) {
            const int c = cc * 256 + t;
            const float sec = se[c];
#pragma unroll
            for (int r = 0; r < RB; ++r) {
                float s = __fsub_rn(__fadd_rn(sxr_s[r], sec), __fmul_rn(2.0f, acc[cc][r]));
                if (s < best[r] || (s == best[r] && c < bidx[r])) { best[r] = s; bidx[r] = c; }
            }
        }
#pragma unroll
        for (int r = 0; r < RB; ++r) { rv[r][t] = best[r]; ri[r][t] = bidx[r]; }
        __syncthreads();

        for (int sft = 128; sft >= 1; sft >>= 1) {
            if (t < sft) {
#pragma unroll
                for (int r = 0; r < RB; ++r) {
                    float ov = rv[r][t + sft];
                    int oi = ri[r][t + sft];
                    if (ov < rv[r][t] || (ov == rv[r][t] && oi < ri[r][t])) {
                        rv[r][t] = ov; ri[r][t] = oi;
                    }
                }
            }
            __syncthreads();
        }
        if (t < nb) {
            int row = rows_s[t];
            int kn = ri[t][0], ko = idx_int[row];
            kn_s[t] = kn; ko_s[t] = ko;
            if (kn != ko) {
                idx_int[row] = kn;
                out_idx[row] = (float)kn;
                atomicAdd(&counts[ko], -1.0f);
                atomicAdd(&counts[kn], 1.0f);
            }
        }
        __syncthreads();

        for (int r = 0; r < nb; ++r) {
            const int ko = ko_s[r], kn = kn_s[r];
            if (kn != ko) {
                const int row = rows_s[r];
                float x = xs[r][t];
                float qo = Wf[(size_t)ko * DD + t];
                float qn = Wf[(size_t)kn * DD + t];
                float dfn = qn - x, dfo = qo - x;
                out_q[(size_t)row * DD + t] = x + dfn;
                double dl = (double)dfn * dfn - (double)dfo * dfo;
                for (int mm = 32; mm >= 1; mm >>= 1) dl += __shfl_xor(dl, mm, 64);
                if ((t & 63) == 0) dred[t >> 6] = dl;
                __syncthreads();
                if (t == 0) atomicAdd(loss_acc, dred[0] + dred[1] + dred[2] + dred[3]);
                __syncthreads();
            }
        }
        __syncthreads();
    }
}

__global__ void finprefix(const float* __restrict__ ema_cs, float* __restrict__ ncs_buf,
                          const double* __restrict__ loss_acc, float* __restrict__ out_loss,
                          float* __restrict__ n_out, int* __restrict__ off,
                          int* __restrict__ cur)
{
    __shared__ float red[1024];
    __shared__ int s[1024];
    int t = threadIdx.x;
    const float OM = (float)(1.0 - 0.99);
    float cnt = ncs_buf[t];
    s[t] = (int)cnt;
    float ncs = __fadd_rn(__fmul_rn(0.99f, ema_cs[t]), __fmul_rn(OM, cnt));
    ncs_buf[t] = ncs;
    red[t] = ncs;
    __syncthreads();
    for (int st = 512; st >= 1; st >>= 1) {
        if (t < st) red[t] += red[t + st];
        __syncthreads();
    }
    if (t == 0) {
        n_out[0] = red[0];
        float el = (float)(loss_acc[0] / 16777216.0);
        out_loss[0] = __fadd_rn(el, __fmul_rn(0.25f, el));
    }
    for (int d = 1; d < 1024; d <<= 1) {
        int v = (t >= d) ? s[t - d] : 0;
        __syncthreads();
        s[t] += v;
        __syncthreads();
    }
    off[t] = (t == 0) ? 0 : s[t - 1];
    cur[t] = 0;
    if (t == 0) off[1024] = NROWS;
}

__global__ __launch_bounds__(256) void scatter_rows(
    const int* __restrict__ idx_int, const int* __restrict__ off,
    int* __restrict__ cur, int* __restrict__ sorted) {
    int i = blockIdx.x * 256 + threadIdx.x;
    int k = idx_int[i];
    int p = atomicAdd(&cur[k], 1);
    sorted[off[k] + p] = i;
}

__global__ __launch_bounds__(256) void embfin2(
    const float* __restrict__ X, const int* __restrict__ off,
    const int* __restrict__ sorted, const float* __restrict__ ema_avg,
    const float* __restrict__ ncs, const float* __restrict__ n_ptr,
    float* __restrict__ out_avg, float* __restrict__ out_w)
{
    const int k = blockIdx.x, t = threadIdx.x;
    const int s0 = off[k], s1 = off[k + 1];
    float a0 = 0.f, a1 = 0.f, a2 = 0.f, a3 = 0.f;
    int i = s0;
    for (; i + 4 <= s1; i += 4) {
        int r0 = sorted[i], r1 = sorted[i + 1], r2 = sorted[i + 2], r3 = sorted[i + 3];
        a0 += X[(size_t)r0 * DD + t];
        a1 += X[(size_t)r1 * DD + t];
        a2 += X[(size_t)r2 * DD + t];
        a3 += X[(size_t)r3 * DD + t];
    }
    for (; i < s1; ++i) a0 += X[(size_t)sorted[i] * DD + t];
    float total = (a0 + a1) + (a2 + a3);

    const float OM = (float)(1.0 - 0.99);
    const float KEPS = (float)(1024.0 * 1e-5);
    size_t o = (size_t)k * DD + t;
    float avg = __fadd_rn(__fmul_rn(0.99f, ema_avg[o]), __fmul_rn(OM, total));
    float n = n_ptr[0];
    float cs = __fmul_rn(__fdiv_rn(__fadd_rn(ncs[k], 1e-5f), __fadd_rn(n, KEPS)), n);
    out_avg[o] = avg;
    out_w[o] = __fdiv_rn(avg, cs);
}

extern "C" void kernel_launch(void* const* d_in, const int* in_sizes, int n_in,
                              void* d_out, int out_size, void* d_ws, size_t ws_size,
                              hipStream_t stream) {
    const float* X = (const float*)d_in[0];
    const float* W = (const float*)d_in[1];
    const float* ema_cs = (const float*)d_in[2];
    const float* ema_avg = (const float*)d_in[3];

    float* out = (float*)d_out;
    float* out_q    = out;
    float* out_loss = out + 16777216;
    float* out_idx  = out + 16777217;
    float* out_w    = out + 16842753;
    float* out_ncs  = out + 17104897;
    float* out_avg  = out + 17105921;

    char* ws = (char*)d_ws;
    float* se      = (float*)(ws + 0);
    float* n_ptr   = (float*)(ws + 4096);
    double* loss   = (double*)(ws + 4112);
    int*   count   = (int*)(ws + 4128);
    _Float16* wh   = (_Float16*)(ws + 8192);
    float* sx      = (float*)(ws + 1056768);
    int*   idx_int = (int*)(ws + 1318912);
    int*   flags   = (int*)(ws + 1581056);
    float4* WT4    = (float4*)(ws + 2097152);
    int*   off     = (int*)(ws + 3145728);
    int*   cur     = (int*)(ws + 3153920);
    int*   sorted  = (int*)(ws + 3158016);

    wprep<<<KC, 64, 0, stream>>>(W, wh, se, WT4, out_ncs, loss, count);
    vq_mfma<<<NROWS / BM, NT, 0, stream>>>(X, wh, se, out_q, out_idx,
                                           idx_int, sx, flags, count,
                                           out_ncs, loss);
    rescue<<<512, 256, 0, stream>>>(X, WT4, W, se, sx, flags, count, idx_int, out_idx,
                                    out_q, out_ncs, loss);
    finprefix<<<1, 1024, 0, stream>>>(ema_cs, out_ncs, loss, out_loss, n_ptr, off, cur);
    scatter_rows<<<NROWS / 256, 256, 0, stream>>>(idx_int, off, cur, sorted);
    embfin2<<<KC, 256, 0, stream>>>(X, off, sorted, ema_avg, out_ncs, n_ptr,
                                    out_avg, out_w);
}